// Round 12
// baseline (516.867 us; speedup 1.0000x reference)
//
#include <hip/hip_runtime.h>
#include <hip/hip_bf16.h>
#include <hip/hip_fp16.h>

// Hyperbolic GNN layer. D = 64.
// R12: obj-bucketed aggregation, take 3. Root causes of R8/R9 fixed:
//   R8: atomicAdd through generic float* param -> flat CAS loop.
//   R9: inline-asm ds_add_f32 with per-op "memory" clobber -> loop serialized.
//   R12: unsafeAtomicAdd on static __shared__ float[] -> native ds_add_f32,
//        no clobbers, compiler free to pipeline the gather loop.
// Pipeline: prep_fused16 -> scatter_edges (bin by obj>>7) -> bucket_edge
// (512 thr, f32 LDS tile, one streaming row write) -> ovf_edge -> final_gemm16.
// Fallbacks: R11 packed-atomic path, R10 atomic path, generic f32.

__device__ __forceinline__ float wave_sum(float v) {
#pragma unroll
    for (int off = 32; off > 0; off >>= 1) v += __shfl_xor(v, off, 64);
    return v;
}

// ---- fast HW math ----
__device__ __forceinline__ float frcp(float x) {
#if __has_builtin(__builtin_amdgcn_rcpf)
    return __builtin_amdgcn_rcpf(x);
#else
    return 1.f / x;
#endif
}
__device__ __forceinline__ float fsqrt_(float x) {
#if __has_builtin(__builtin_amdgcn_sqrtf)
    return __builtin_amdgcn_sqrtf(x);
#else
    return sqrtf(x);
#endif
}
__device__ __forceinline__ float flog2_(float x) {
#if __has_builtin(__builtin_amdgcn_logf)
    return __builtin_amdgcn_logf(x);
#else
    return log2f(x);
#endif
}
__device__ __forceinline__ float fexp2_(float x) {
#if __has_builtin(__builtin_amdgcn_exp2f)
    return __builtin_amdgcn_exp2f(x);
#else
    return exp2f(x);
#endif
}
__device__ __forceinline__ float ftanh_pos(float x) {
    return 1.f - 2.f * frcp(fexp2_(x * 2.885390082f) + 1.f);
}

__device__ __forceinline__ unsigned pk2(float a, float b) {
    __half2 h = __floats2half2_rn(a, b);
    return __builtin_bit_cast(unsigned, h);
}
__device__ __forceinline__ float2 upk2(unsigned u) {
    __half2 h = __builtin_bit_cast(__half2, u);
    return __half22float2(h);
}

__device__ __forceinline__ void expmap0_scale(float norm, float& s, float& x2) {
    const float maxn = 1.0f - 0.004f;
    float un = fmaxf(norm, 1e-15f);
    float th = ftanh_pos(fminf(un, 15.0f));
    float gs = th * frcp(un);
    float ng = gs * norm;
    float ps = ng > maxn ? maxn * frcp(ng) : 1.0f;
    s = gs * ps;
    float sn = s * norm;
    x2 = sn * sn;
}

// ================= per-edge math (quad = 16 lanes/edge) =================
// returns (cx, cy): msg = cx*h + cy*y
__device__ __forceinline__ float2 edge_coef(
    unsigned hu_lo, unsigned hu_hi, unsigned yu_lo, unsigned yu_hi,
    uint4 hsa, uint4 hra, uint4 pqa, const float* wa, float wb) {
    float2 hs01 = upk2(hsa.x), hs23 = upk2(hsa.y), hs4 = upk2(hsa.z), hsxs = upk2(hsa.w);
    float2 hr01 = upk2(hra.x), hr23 = upk2(hra.y), hr4 = upk2(hra.z), hry = upk2(hra.w);
    float2 pq01 = upk2(pqa.x), pq23 = upk2(pqa.y), pq4 = upk2(pqa.z);
    float x2 = hsxs.x, s = hsxs.y, y2 = hry.x;

    float2 hl = upk2(hu_lo), hh = upk2(hu_hi);
    float2 yl = upk2(yu_lo), yh = upk2(yu_hi);

    float p = hl.x * yl.x;
    p = fmaf(hl.y, yl.y, p);
    p = fmaf(hh.x, yh.x, p);
    p = fmaf(hh.y, yh.y, p);
    p += __shfl_xor(p, 1, 64);
    p += __shfl_xor(p, 2, 64);
    p += __shfl_xor(p, 4, 64);
    p += __shfl_xor(p, 8, 64);
    float xy = p * s;

    float z = wb;
    z = fmaf(fmaxf(hs01.x + hr01.x + pq01.x, 0.f), wa[0], z);
    z = fmaf(fmaxf(hs01.y + hr01.y + pq01.y, 0.f), wa[1], z);
    z = fmaf(fmaxf(hs23.x + hr23.x + pq23.x, 0.f), wa[2], z);
    z = fmaf(fmaxf(hs23.y + hr23.y + pq23.y, 0.f), wa[3], z);
    z = fmaf(fmaxf(hs4.x + hr4.x + pq4.x, 0.f), wa[4], z);
    float alpha = frcp(1.f + fexp2_(z * -1.44269504f));

    float Af  = 1.f + 2.f * xy + y2;
    float Bf  = 1.f - x2;
    float den = fmaxf(1.f + 2.f * xy + x2 * y2, 1e-15f);
    float inv = frcp(den);
    float nm2 = fmaxf(fmaf(Af * Af, x2, fmaf(2.f * Af * Bf, xy, Bf * Bf * y2)), 0.f);
    float nm  = fsqrt_(nm2) * inv;
    const float maxn = 1.0f - 0.004f;
    float ps  = nm > maxn ? maxn * frcp(nm) : 1.f;
    float yn  = fmaxf(fminf(nm, maxn), 1e-15f);
    float ratio = (1.f + yn) * frcp(1.f - yn);
    float art = 0.34657359f * flog2_(ratio);
    float k  = inv * ps * alpha * art * frcp(yn);
    return make_float2(k * Af * s, k * Bf);
}

__device__ __forceinline__ void edge_to_global(
    unsigned hu_lo, unsigned hu_hi, unsigned yu_lo, unsigned yu_hi,
    uint4 hsa, uint4 hra, uint4 pqa, const float* wa, float wb,
    bool act, __half2* dst /* agg + obj*32 + j */) {
    float2 c = edge_coef(hu_lo, hu_hi, yu_lo, yu_hi, hsa, hra, pqa, wa, wb);
    float2 hl = upk2(hu_lo), hh = upk2(hu_hi);
    float2 yl = upk2(yu_lo), yh = upk2(yu_hi);
    __half2 q_lo = __floats2half2_rn(fmaf(c.x, hl.x, c.y * yl.x), fmaf(c.x, hl.y, c.y * yl.y));
    __half2 q_hi = __floats2half2_rn(fmaf(c.x, hh.x, c.y * yh.x), fmaf(c.x, hh.y, c.y * yh.y));
    if (act) {
        unsafeAtomicAdd(dst, q_lo);
        unsafeAtomicAdd(dst + 16, q_hi);
    }
}

// ================= prep (+ optional edge packing for R11 path) =================
__global__ void prep_fused16(const int* __restrict__ q_rel,
                             const float* __restrict__ query_embed,
                             const float* __restrict__ Wqr_w,
                             const float* __restrict__ Wqr_b,
                             const float* __restrict__ rela_embed,
                             const float* __restrict__ Wr,
                             const float* __restrict__ hidden,
                             const float* __restrict__ Ws,
                             const int* __restrict__ edges,
                             __half* __restrict__ hidden16,
                             uint4* __restrict__ hs_aux16,
                             __half* __restrict__ hr_h16,
                             uint4* __restrict__ hr_aux16,
                             uint4* __restrict__ preq16,
                             __half* __restrict__ agg16,
                             unsigned long long* __restrict__ packed,
                             int N, int R, int B, int E, int zero_agg) {
    int wid = (blockIdx.x * blockDim.x + threadIdx.x) >> 6;
    int lane = threadIdx.x & 63;
    int nwaves = (N + 3) >> 2;
    if (wid < nwaves) {
        int q = lane >> 4, j = lane & 15;
        int n = wid * 4 + q;
        bool act = n < N;
        int nc = act ? n : N - 1;

        float4 u = *(const float4*)(hidden + (size_t)nc * 64 + 4 * j);
        float4 w0 = *(const float4*)(Ws + 0 * 64 + 4 * j);
        float4 w1 = *(const float4*)(Ws + 1 * 64 + 4 * j);
        float4 w2 = *(const float4*)(Ws + 2 * 64 + 4 * j);
        float4 w3 = *(const float4*)(Ws + 3 * 64 + 4 * j);
        float4 w4 = *(const float4*)(Ws + 4 * 64 + 4 * j);

#define DOT4(a, b) (fmaf((a).x, (b).x, fmaf((a).y, (b).y, fmaf((a).z, (b).z, (a).w * (b).w))))
        float p0 = DOT4(u, u);
        float p1 = DOT4(u, w0);
        float p2 = DOT4(u, w1);
        float p3 = DOT4(u, w2);
        float p4 = DOT4(u, w3);
        float p5 = DOT4(u, w4);
#undef DOT4
#pragma unroll
        for (int off = 1; off < 16; off <<= 1) {
            p0 += __shfl_xor(p0, off, 64);
            p1 += __shfl_xor(p1, off, 64);
            p2 += __shfl_xor(p2, off, 64);
            p3 += __shfl_xor(p3, off, 64);
            p4 += __shfl_xor(p4, off, 64);
            p5 += __shfl_xor(p5, off, 64);
        }
        float s, x2;
        expmap0_scale(fsqrt_(p0), s, x2);
        if (act) {
            uint2 hp; hp.x = pk2(u.x, u.y); hp.y = pk2(u.z, u.w);
            *(uint2*)(hidden16 + (size_t)n * 64 + 4 * j) = hp;
            if (zero_agg) {
                uint2 zz; zz.x = 0u; zz.y = 0u;
                ((uint2*)(agg16 + (size_t)n * 64))[j] = zz;
            }
            if (j == 0) {
                uint4 o; o.x = pk2(p1, p2); o.y = pk2(p3, p4); o.z = pk2(p5, 0.f); o.w = pk2(x2, s);
                hs_aux16[n] = o;
            }
        }
        return;
    }
    int w2 = wid - nwaves;
    if (w2 < R) {
        int r = w2;
        float u = rela_embed[r * 64 + lane];
        float p0 = u * u;
        float p1 = u * Wr[0 * 64 + lane];
        float p2 = u * Wr[1 * 64 + lane];
        float p3 = u * Wr[2 * 64 + lane];
        float p4 = u * Wr[3 * 64 + lane];
        float p5 = u * Wr[4 * 64 + lane];
#pragma unroll
        for (int off = 1; off < 64; off <<= 1) {
            p0 += __shfl_xor(p0, off, 64);
            p1 += __shfl_xor(p1, off, 64);
            p2 += __shfl_xor(p2, off, 64);
            p3 += __shfl_xor(p3, off, 64);
            p4 += __shfl_xor(p4, off, 64);
            p5 += __shfl_xor(p5, off, 64);
        }
        float s, y2;
        expmap0_scale(fsqrt_(p0), s, y2);
        hr_h16[r * 64 + lane] = __float2half(s * u);
        if (lane == 0) {
            uint4 o; o.x = pk2(p1, p2); o.y = pk2(p3, p4); o.z = pk2(p5, 0.f); o.w = pk2(y2, 0.f);
            hr_aux16[r] = o;
        }
        return;
    }
    int w3 = w2 - R;
    if (w3 < B) {
        int b = w3;
        int qr = q_rel[b];
        float q = query_embed[qr * 64 + lane];
        float p1 = q * Wqr_w[0 * 64 + lane];
        float p2 = q * Wqr_w[1 * 64 + lane];
        float p3 = q * Wqr_w[2 * 64 + lane];
        float p4 = q * Wqr_w[3 * 64 + lane];
        float p5 = q * Wqr_w[4 * 64 + lane];
#pragma unroll
        for (int off = 1; off < 64; off <<= 1) {
            p1 += __shfl_xor(p1, off, 64);
            p2 += __shfl_xor(p2, off, 64);
            p3 += __shfl_xor(p3, off, 64);
            p4 += __shfl_xor(p4, off, 64);
            p5 += __shfl_xor(p5, off, 64);
        }
        if (lane == 0) {
            uint4 o;
            o.x = pk2(p1 + Wqr_b[0], p2 + Wqr_b[1]);
            o.y = pk2(p3 + Wqr_b[2], p4 + Wqr_b[3]);
            o.z = pk2(p5 + Wqr_b[4], 0.f);
            o.w = pk2(0.f, 0.f);
            preq16[b] = o;
        }
        return;
    }
    // optional edge packing (R11 fallback path only; E==0 on bucket path)
    int w4 = w3 - B;
    int e = w4 * 64 + lane;
    if (e < E) {
        const int* er = edges + (size_t)e * 6;
        int ri  = er[0];
        int rel = er[2];
        int sub = er[4];
        int obj = er[5];
        unsigned long long pk = (unsigned long long)(unsigned)(obj & 0x1ffff)
            | ((unsigned long long)(unsigned)(sub & 0x1ffff) << 17)
            | ((unsigned long long)(unsigned)(rel & 0x1ff) << 34)
            | ((unsigned long long)(unsigned)(ri & 0x1ff) << 43);
        __builtin_nontemporal_store(pk, &packed[e]);
    }
}

// ================= bucketed path =================

__global__ void init_cur(int* __restrict__ cur, int NB, int cap) {
    int i = blockIdx.x * blockDim.x + threadIdx.x;
    if (i < NB) cur[i] = i * cap;
    else if (i == NB) cur[i] = 0;   // overflow counter
}

// pack + bin edges by obj>>7. 4096 edges/block. (validated in R8/R9)
__global__ __launch_bounds__(256) void scatter_edges(
    const int* __restrict__ edges, int E, int NB, int cap,
    int* __restrict__ cur,
    unsigned long long* __restrict__ bbuf,
    unsigned long long* __restrict__ ovfbuf, int ovfcap)
{
    __shared__ unsigned long long spk[4096];
    __shared__ int lh[1024];
    __shared__ int lb[1024];
    int t = threadIdx.x;
    int base = blockIdx.x * 4096;
    for (int i = t; i < NB; i += 256) lh[i] = 0;
    __syncthreads();
    int nloc = min(4096, E - base);
    for (int k = t; k < nloc; k += 256) {
        const long long* er = (const long long*)(edges + (size_t)(base + k) * 6);
        long long a = er[0], bq = er[1], cq = er[2];
        int ri = (int)a, rel = (int)bq, sub = (int)cq, obj = (int)(cq >> 32);
        unsigned long long pk = (unsigned long long)(unsigned)(obj & 0x1ffff)
            | ((unsigned long long)(unsigned)(sub & 0x1ffff) << 17)
            | ((unsigned long long)(unsigned)(rel & 0x1ff) << 34)
            | ((unsigned long long)(unsigned)(ri & 0x1ff) << 43);
        spk[k] = pk;
        atomicAdd(&lh[obj >> 7], 1);
    }
    __syncthreads();
    for (int i = t; i < NB; i += 256) {
        int c = lh[i];
        lb[i] = c ? atomicAdd(&cur[i], c) : 0;
    }
    __syncthreads();
    for (int i = t; i < NB; i += 256) lh[i] = 0;
    __syncthreads();
    for (int k = t; k < nloc; k += 256) {
        unsigned long long pk = spk[k];
        int bk = (int)(pk & 0x1ffff) >> 7;
        int rank = atomicAdd(&lh[bk], 1);
        int slot = lb[bk] + rank;
        if (slot < (bk + 1) * cap) {
            bbuf[slot] = pk;
        } else {
            int o = atomicAdd(cur + NB, 1);
            if (o < ovfcap) ovfbuf[o] = pk;
        }
    }
}

// one block (512 thr = 8 waves) per 128-node bucket.
// Native ds_add_f32 via unsafeAtomicAdd on the static __shared__ array;
// NO asm, NO memory clobbers -> gather loop pipelines freely.
__global__ __launch_bounds__(512) void bucket_edge(
    const unsigned long long* __restrict__ bbuf,
    const int* __restrict__ cur, int cap, int N,
    const __half* __restrict__ hidden16,
    const __half* __restrict__ hr_h16,
    const uint4* __restrict__ hs_aux16,
    const uint4* __restrict__ hr_aux16,
    const uint4* __restrict__ preq16,
    const float* __restrict__ walpha_w,
    const float* __restrict__ walpha_b,
    __half* __restrict__ agg16)
{
    __shared__ float agg[128 * 65];   // 33.28 KB, stride 65 (2-way aliasing = free)
    int b = blockIdx.x;
    int t = threadIdx.x;
    for (int i = t; i < 128 * 65; i += 512) agg[i] = 0.f;

    float wa[5];
    wa[0] = walpha_w[0]; wa[1] = walpha_w[1]; wa[2] = walpha_w[2];
    wa[3] = walpha_w[3]; wa[4] = walpha_w[4];
    float wb = walpha_b[0];

    __syncthreads();

    int start = b * cap;
    int cnt = min(cur[b] - start, cap);
    int lane = t & 63;
    int w = t >> 6;          // 8 waves
    int g = lane >> 4;
    int j = lane & 15;

    for (int it = w * 8; it < cnt; it += 64) {
        int i0 = it + g, i1 = it + 4 + g;
        bool a0 = i0 < cnt, a1 = i1 < cnt;
        unsigned long long p0 = bbuf[start + (a0 ? i0 : 0)];
        unsigned long long p1 = bbuf[start + (a1 ? i1 : 0)];
        int obj0 = (int)(p0 & 0x1ffff), sub0 = (int)((p0 >> 17) & 0x1ffff);
        int rel0 = (int)((p0 >> 34) & 0x1ff), ri0 = (int)((p0 >> 43) & 0x1ff);
        int obj1 = (int)(p1 & 0x1ffff), sub1 = (int)((p1 >> 17) & 0x1ffff);
        int rel1 = (int)((p1 >> 34) & 0x1ff), ri1 = (int)((p1 >> 43) & 0x1ff);

        uint4 hsa0 = hs_aux16[sub0], hra0 = hr_aux16[rel0], pqa0 = preq16[ri0];
        uint4 hsa1 = hs_aux16[sub1], hra1 = hr_aux16[rel1], pqa1 = preq16[ri1];
        const unsigned* hrow0 = (const unsigned*)(hidden16 + (size_t)sub0 * 64);
        const unsigned* yrow0 = (const unsigned*)(hr_h16 + (size_t)rel0 * 64);
        const unsigned* hrow1 = (const unsigned*)(hidden16 + (size_t)sub1 * 64);
        const unsigned* yrow1 = (const unsigned*)(hr_h16 + (size_t)rel1 * 64);
        unsigned hu_lo0 = hrow0[j], hu_hi0 = hrow0[16 + j];
        unsigned yu_lo0 = yrow0[j], yu_hi0 = yrow0[16 + j];
        unsigned hu_lo1 = hrow1[j], hu_hi1 = hrow1[16 + j];
        unsigned yu_lo1 = yrow1[j], yu_hi1 = yrow1[16 + j];

        float2 c0 = edge_coef(hu_lo0, hu_hi0, yu_lo0, yu_hi0, hsa0, hra0, pqa0, wa, wb);
        float2 c1 = edge_coef(hu_lo1, hu_hi1, yu_lo1, yu_hi1, hsa1, hra1, pqa1, wa, wb);

        float2 hl0 = upk2(hu_lo0), hh0 = upk2(hu_hi0), vl0 = upk2(yu_lo0), vh0 = upk2(yu_hi0);
        float2 hl1 = upk2(hu_lo1), hh1 = upk2(hu_hi1), vl1 = upk2(yu_lo1), vh1 = upk2(yu_hi1);

        if (a0) {
            int ix = (obj0 & 127) * 65 + 2 * j;
            unsafeAtomicAdd(&agg[ix],      fmaf(c0.x, hl0.x, c0.y * vl0.x));
            unsafeAtomicAdd(&agg[ix + 1],  fmaf(c0.x, hl0.y, c0.y * vl0.y));
            unsafeAtomicAdd(&agg[ix + 32], fmaf(c0.x, hh0.x, c0.y * vh0.x));
            unsafeAtomicAdd(&agg[ix + 33], fmaf(c0.x, hh0.y, c0.y * vh0.y));
        }
        if (a1) {
            int ix = (obj1 & 127) * 65 + 2 * j;
            unsafeAtomicAdd(&agg[ix],      fmaf(c1.x, hl1.x, c1.y * vl1.x));
            unsafeAtomicAdd(&agg[ix + 1],  fmaf(c1.x, hl1.y, c1.y * vl1.y));
            unsafeAtomicAdd(&agg[ix + 32], fmaf(c1.x, hh1.x, c1.y * vh1.x));
            unsafeAtomicAdd(&agg[ix + 33], fmaf(c1.x, hh1.y, c1.y * vh1.y));
        }
    }
    __syncthreads();

    int nbase = b << 7;
    for (int i = t; i < 128 * 32; i += 512) {
        int r = i >> 5, c = i & 31;
        int n = nbase + r;
        if (n < N) {
            unsigned v = pk2(agg[r * 65 + 2 * c], agg[r * 65 + 2 * c + 1]);
            __builtin_nontemporal_store(v, (unsigned*)(agg16 + (size_t)n * 64) + c);
        }
    }
}

// overflow edges (expected none): global f16 atomics
__global__ __launch_bounds__(256) void ovf_edge(
    const unsigned long long* __restrict__ ovfbuf,
    const int* __restrict__ ovfcnt_p, int ovfcap,
    const __half* __restrict__ hidden16,
    const __half* __restrict__ hr_h16,
    const uint4* __restrict__ hs_aux16,
    const uint4* __restrict__ hr_aux16,
    const uint4* __restrict__ preq16,
    const float* __restrict__ walpha_w,
    const float* __restrict__ walpha_b,
    __half2* __restrict__ agg)
{
    int cnt = min(*ovfcnt_p, ovfcap);
    if (cnt <= 0) return;
    int j = threadIdx.x & 15;
    int qid = (blockIdx.x * blockDim.x + threadIdx.x) >> 4;
    int nq = (gridDim.x * blockDim.x) >> 4;
    float wa[5];
    wa[0] = walpha_w[0]; wa[1] = walpha_w[1]; wa[2] = walpha_w[2];
    wa[3] = walpha_w[3]; wa[4] = walpha_w[4];
    float wb = walpha_b[0];
    for (int e = qid; e < cnt; e += nq) {
        unsigned long long pk = ovfbuf[e];
        int obj = (int)(pk & 0x1ffff), sub = (int)((pk >> 17) & 0x1ffff);
        int rel = (int)((pk >> 34) & 0x1ff), ri = (int)((pk >> 43) & 0x1ff);
        uint4 hsa = hs_aux16[sub], hra = hr_aux16[rel], pqa = preq16[ri];
        const unsigned* hrow = (const unsigned*)(hidden16 + (size_t)sub * 64);
        const unsigned* yrow = (const unsigned*)(hr_h16 + (size_t)rel * 64);
        edge_to_global(hrow[j], hrow[16 + j], yrow[j], yrow[16 + j],
                       hsa, hra, pqa, wa, wb, true, agg + (size_t)obj * 32 + j);
    }
}

// ================= R11 fallback edge kernel (packed, atomic) =================
__global__ __launch_bounds__(256) void edge_kernel8p(
    const unsigned long long* __restrict__ packed,
    const __half* __restrict__ hidden16,
    const __half* __restrict__ hr_h16,
    const uint4* __restrict__ hs_aux16,
    const uint4* __restrict__ hr_aux16,
    const uint4* __restrict__ preq16,
    const float* __restrict__ walpha_w,
    const float* __restrict__ walpha_b,
    __half2* __restrict__ agg,
    int E)
{
    int wid = (blockIdx.x * blockDim.x + threadIdx.x) >> 6;
    int lane = threadIdx.x & 63;
    int g = lane >> 4;
    int j = lane & 15;

    int e0 = wid * 8 + g;
    int e1 = wid * 8 + 4 + g;
    bool act0 = e0 < E, act1 = e1 < E;

    unsigned long long p0 = __builtin_nontemporal_load(&packed[act0 ? e0 : 0]);
    unsigned long long p1 = __builtin_nontemporal_load(&packed[act1 ? e1 : 0]);
    int obj0 = (int)(p0 & 0x1ffff), sub0 = (int)((p0 >> 17) & 0x1ffff);
    int rel0 = (int)((p0 >> 34) & 0x1ff), r0 = (int)((p0 >> 43) & 0x1ff);
    int obj1 = (int)(p1 & 0x1ffff), sub1 = (int)((p1 >> 17) & 0x1ffff);
    int rel1 = (int)((p1 >> 34) & 0x1ff), r1 = (int)((p1 >> 43) & 0x1ff);

    uint4 hsa0 = hs_aux16[sub0], hra0 = hr_aux16[rel0], pqa0 = preq16[r0];
    uint4 hsa1 = hs_aux16[sub1], hra1 = hr_aux16[rel1], pqa1 = preq16[r1];

    const unsigned* hrow0 = (const unsigned*)(hidden16 + (size_t)sub0 * 64);
    const unsigned* yrow0 = (const unsigned*)(hr_h16 + (size_t)rel0 * 64);
    const unsigned* hrow1 = (const unsigned*)(hidden16 + (size_t)sub1 * 64);
    const unsigned* yrow1 = (const unsigned*)(hr_h16 + (size_t)rel1 * 64);

    float wa[5];
    wa[0] = walpha_w[0]; wa[1] = walpha_w[1]; wa[2] = walpha_w[2];
    wa[3] = walpha_w[3]; wa[4] = walpha_w[4];
    float wb = walpha_b[0];

    edge_to_global(hrow0[j], hrow0[16 + j], yrow0[j], yrow0[16 + j],
                   hsa0, hra0, pqa0, wa, wb, act0, agg + (size_t)obj0 * 32 + j);
    edge_to_global(hrow1[j], hrow1[16 + j], yrow1[j], yrow1[16 + j],
                   hsa1, hra1, pqa1, wa, wb, act1, agg + (size_t)obj1 * 32 + j);
}

// ================= final: one 64-row tile per block =================
__global__ __launch_bounds__(256) void final_gemm16(
    float* __restrict__ out,
    const __half* __restrict__ agg16,
    const float* __restrict__ Wh,
    int N)
{
    __shared__ __half tile[64 * 64];
    int t = threadIdx.x;
    int lane = t & 63;
    int w = t >> 6;

    float wh[64];
    const float4* whr = (const float4*)(Wh + (size_t)lane * 64);
#pragma unroll
    for (int i = 0; i < 16; ++i) {
        float4 v = whr[i];
        wh[4 * i] = v.x; wh[4 * i + 1] = v.y; wh[4 * i + 2] = v.z; wh[4 * i + 3] = v.w;
    }

    int base = blockIdx.x << 6;
    int nrow = min(64, N - base);
    {
        const uint2* src = (const uint2*)(agg16 + (size_t)base * 64);
        uint2* dst = (uint2*)tile;
        int nu2 = nrow * 16;
        for (int i = t; i < nu2; i += 256) dst[i] = src[i];
    }
    __syncthreads();

#pragma unroll 1
    for (int r = 0; r < 16; ++r) {
        int n = base + w * 16 + r;
        if (n >= N) break;
        const uint2* arow = (const uint2*)(tile + (w * 16 + r) * 64);
        float acc = 0.f;
#pragma unroll
        for (int kk = 0; kk < 16; ++kk) {
            uint2 u = arow[kk];
            float2 f0 = upk2(u.x), f1 = upk2(u.y);
            acc = fmaf(f0.x, wh[4 * kk], acc);
            acc = fmaf(f0.y, wh[4 * kk + 1], acc);
            acc = fmaf(f1.x, wh[4 * kk + 2], acc);
            acc = fmaf(f1.y, wh[4 * kk + 3], acc);
        }
        float n2 = wave_sum(acc * acc);
        float na = fsqrt_(n2);
        float nv = fmaxf(na, 1e-10f);
        float pn = ftanh_pos(nv);
        float rinv = frcp(nv);
        float pp = pn * acc * rinv;
        float np = pn * (na * rinv);
        float yn = fmaxf(np, 1e-15f);
        float tt = fminf(yn, 1.f - 1e-5f);
        float ratio = (1.f + tt) * frcp(1.f - tt);
        float art = 0.34657359f * flog2_(ratio);
        __builtin_nontemporal_store(pp * art * frcp(yn), &out[(size_t)n * 64 + lane]);
    }
}

// ================= generic fallback (any A, f32) =================

__global__ void prep_small_kernel(const int* __restrict__ q_rel,
                                  const float* __restrict__ query_embed,
                                  const float* __restrict__ Wqr_w,
                                  const float* __restrict__ Wqr_b,
                                  const float* __restrict__ rela_embed,
                                  const float* __restrict__ Wr,
                                  float* __restrict__ hr_h,
                                  float* __restrict__ hr_aux,
                                  float* __restrict__ preq,
                                  int R, int B, int A) {
    int w = (blockIdx.x * blockDim.x + threadIdx.x) >> 6;
    int lane = threadIdx.x & 63;
    if (w < R) {
        int r = w;
        float u = rela_embed[r * 64 + lane];
        float n2 = wave_sum(u * u);
        float s, y2;
        expmap0_scale(fsqrt_(n2), s, y2);
        hr_h[r * 64 + lane] = s * u;
        for (int a = 0; a < A; ++a) {
            float p = wave_sum(u * Wr[a * 64 + lane]);
            if (lane == 0) hr_aux[r * 8 + a] = p;
        }
        if (lane == 0) hr_aux[r * 8 + 6] = y2;
    } else if (w < R + B) {
        int b = w - R;
        int qr = q_rel[b];
        float q = query_embed[qr * 64 + lane];
        for (int a = 0; a < A; ++a) {
            float p = wave_sum(q * Wqr_w[a * 64 + lane]);
            if (lane == 0) preq[b * 8 + a] = p + Wqr_b[a];
        }
    }
}

__global__ void prep_node_kernel(const float* __restrict__ hidden,
                                 const float* __restrict__ Ws,
                                 float* __restrict__ hs_aux, int N, int A) {
    int w = (blockIdx.x * blockDim.x + threadIdx.x) >> 6;
    if (w >= N) return;
    int lane = threadIdx.x & 63;
    float u = hidden[(size_t)w * 64 + lane];
    float n2 = wave_sum(u * u);
    float s, x2;
    expmap0_scale(fsqrt_(n2), s, x2);
    for (int a = 0; a < A; ++a) {
        float p = wave_sum(u * Ws[a * 64 + lane]);
        if (lane == 0) hs_aux[w * 8 + a] = p;
    }
    if (lane == 0) { hs_aux[w * 8 + 6] = x2; hs_aux[w * 8 + 7] = s; }
}

__global__ void edge_kernel_f32(const int* __restrict__ edges,
                                const float* __restrict__ hidden,
                                const float* __restrict__ hr_h,
                                const float* __restrict__ hr_aux,
                                const float* __restrict__ hs_aux,
                                const float* __restrict__ preq,
                                const float* __restrict__ walpha_w,
                                const float* __restrict__ walpha_b,
                                float* __restrict__ agg,
                                int E, int A) {
    int w = (blockIdx.x * blockDim.x + threadIdx.x) >> 6;
    if (w >= E) return;
    int lane = threadIdx.x & 63;
    const int* er = edges + (size_t)w * 6;
    int r_idx = er[0], rel = er[2], sub = er[4], obj = er[5];

    float s  = hs_aux[(size_t)sub * 8 + 7];
    float x2 = hs_aux[(size_t)sub * 8 + 6];
    float h  = hidden[(size_t)sub * 64 + lane];
    float x  = h * s;
    float y  = hr_h[(size_t)rel * 64 + lane];
    float y2 = hr_aux[(size_t)rel * 8 + 6];
    float xy = wave_sum(x * y);

    float z = walpha_b[0];
    for (int a = 0; a < A; ++a) {
        float pre = hs_aux[(size_t)sub * 8 + a] + hr_aux[(size_t)rel * 8 + a] + preq[(size_t)r_idx * 8 + a];
        z += fmaxf(pre, 0.f) * walpha_w[a];
    }
    float alpha = frcp(1.f + fexp2_(z * -1.44269504f));

    float Af = 1.f + 2.f * xy + y2;
    float Bf = 1.f - x2;
    float den = fmaxf(1.f + 2.f * xy + x2 * y2, 1e-15f);
    float inv = frcp(den);
    float nm2 = fmaxf(Af * Af * x2 + 2.f * Af * Bf * xy + Bf * Bf * y2, 0.f);
    float nm = fsqrt_(nm2) * inv;
    const float maxn = 1.0f - 0.004f;
    float ps = nm > maxn ? maxn * frcp(nm) : 1.f;
    float yn = fmaxf(fminf(nm, maxn), 1e-15f);
    float ratio = (1.f + yn) * frcp(1.f - yn);
    float art = 0.34657359f * flog2_(ratio);
    float k = inv * ps * alpha * art * frcp(yn);
    float msg = fmaf(k * Af * s, h, k * Bf * y);
    unsafeAtomicAdd(agg + (size_t)obj * 64 + lane, msg);
}

__global__ void final_kernel_f32(float* __restrict__ out,
                                 const float* __restrict__ Wh,
                                 int N) {
    __shared__ float WhT[64 * 64];
    int t = threadIdx.x;
    for (int i = t; i < 64 * 64; i += blockDim.x) {
        int row = i >> 6, col = i & 63;
        WhT[col * 64 + row] = Wh[i];
    }
    __syncthreads();

    int lane = t & 63;
    int wl = t >> 6;
    int wpb = blockDim.x >> 6;
    int wg = blockIdx.x * wpb + wl;
    int wstride = gridDim.x * wpb;

    for (int n = wg; n < N; n += wstride) {
        float v = out[(size_t)n * 64 + lane];
        float a = 0.f;
#pragma unroll
        for (int k = 0; k < 64; ++k)
            a = fmaf(__shfl(v, k, 64), WhT[k * 64 + lane], a);

        float n2 = wave_sum(a * a);
        float na = fsqrt_(n2);
        float nv = fmaxf(na, 1e-10f);
        float pn = tanhf(nv);
        float rinv = frcp(nv);
        float pp = pn * a * rinv;
        float np = pn * (na * rinv);
        float yn = fmaxf(np, 1e-15f);
        float tt = fminf(yn, 1.f - 1e-5f);
        float ratio = (1.f + tt) * frcp(1.f - tt);
        float art = 0.34657359f * flog2_(ratio);
        out[(size_t)n * 64 + lane] = pp * art * frcp(yn);
    }
}

extern "C" void kernel_launch(void* const* d_in, const int* in_sizes, int n_in,
                              void* d_out, int out_size, void* d_ws, size_t ws_size,
                              hipStream_t stream) {
    const int*   q_rel       = (const int*)d_in[1];
    const float* hidden      = (const float*)d_in[2];
    const int*   edges       = (const int*)d_in[3];
    const float* rela_embed  = (const float*)d_in[6];
    const float* query_embed = (const float*)d_in[7];
    const float* Ws          = (const float*)d_in[8];
    const float* Wr          = (const float*)d_in[9];
    const float* Wqr_w       = (const float*)d_in[10];
    const float* Wqr_b       = (const float*)d_in[11];
    const float* walpha_w    = (const float*)d_in[12];
    const float* walpha_b    = (const float*)d_in[13];
    const float* Wh          = (const float*)d_in[14];

    const int D = 64;
    int B = in_sizes[0];
    int E = in_sizes[3] / 6;
    int A = in_sizes[11];
    int R = in_sizes[6] / D;
    int N = out_size / D;

    float* out = (float*)d_out;

    size_t agg_b    = (size_t)N * 128;
    size_t hid16_b  = (size_t)N * 128;
    size_t hsaux_b  = (size_t)N * 16;
    size_t hrh_b    = (size_t)R * 128;
    size_t hraux_b  = (size_t)R * 16;
    size_t preq_b   = (size_t)B * 16;
    size_t need16   = agg_b + hid16_b + hsaux_b + hrh_b + hraux_b + preq_b;
    size_t packed_b = (size_t)E * 8;
    size_t need_pk  = need16 + packed_b;

    int NB = (N + 127) >> 7;
    int cap = (NB > 0) ? 2 * ((E + NB - 1) / NB) : 512;
    if (cap < 512) cap = 512;
    int ovfcap = 65536;
    size_t bbuf_b = (size_t)NB * (size_t)cap * 8;
    size_t cur_b  = (((size_t)NB + 1) * 4 + 15) & ~(size_t)15;
    size_t ovf_b  = (size_t)ovfcap * 8;
    size_t need_bucket = need16 + bbuf_b + cur_b + ovf_b;

    bool fields_ok = (N > 0) && (N <= 131072) && (R <= 512) && (B <= 512);
    bool bucket_ok = (A == 5) && fields_ok && (NB <= 1024) && (E > 0) &&
                     ((long long)NB * cap < (1LL << 31)) && (ws_size >= need_bucket);
    bool pkpath = (A == 5) && fields_ok && (ws_size >= need_pk);
    bool f16path = (A == 5) && (ws_size >= need16);

    if (bucket_ok) {
        char* base = (char*)d_ws;
        __half* agg16    = (__half*)base;            base += agg_b;
        __half* hidden16 = (__half*)base;            base += hid16_b;
        uint4*  hs_aux16 = (uint4*)base;             base += hsaux_b;
        __half* hr_h16   = (__half*)base;            base += hrh_b;
        uint4*  hr_aux16 = (uint4*)base;             base += hraux_b;
        uint4*  preq16   = (uint4*)base;             base += preq_b;
        unsigned long long* bbuf = (unsigned long long*)base; base += bbuf_b;
        int* cur = (int*)base;                       base += cur_b;
        unsigned long long* ovfbuf = (unsigned long long*)base;

        init_cur<<<(NB + 1 + 255) / 256, 256, 0, stream>>>(cur, NB, cap);

        int nwaves = (N + 3) / 4;
        int total_waves = nwaves + R + B;
        prep_fused16<<<(total_waves + 3) / 4, 256, 0, stream>>>(
            q_rel, query_embed, Wqr_w, Wqr_b, rela_embed, Wr,
            hidden, Ws, edges, hidden16, hs_aux16, hr_h16, hr_aux16, preq16,
            agg16, (unsigned long long*)nullptr, N, R, B, 0, /*zero_agg=*/0);

        scatter_edges<<<(E + 4095) / 4096, 256, 0, stream>>>(
            edges, E, NB, cap, cur, bbuf, ovfbuf, ovfcap);

        bucket_edge<<<NB, 512, 0, stream>>>(
            bbuf, cur, cap, N, hidden16, hr_h16, hs_aux16, hr_aux16, preq16,
            walpha_w, walpha_b, agg16);

        ovf_edge<<<64, 256, 0, stream>>>(
            ovfbuf, cur + NB, ovfcap, hidden16, hr_h16, hs_aux16, hr_aux16,
            preq16, walpha_w, walpha_b, (__half2*)agg16);

        int ntiles = (N + 63) / 64;
        final_gemm16<<<ntiles, 256, 0, stream>>>(out, agg16, Wh, N);
    } else if (pkpath) {
        char* base = (char*)d_ws;
        __half2* agg      = (__half2*)base;          base += agg_b;
        __half*  hidden16 = (__half*)base;           base += hid16_b;
        uint4*   hs_aux16 = (uint4*)base;            base += hsaux_b;
        __half*  hr_h16   = (__half*)base;           base += hrh_b;
        uint4*   hr_aux16 = (uint4*)base;            base += hraux_b;
        uint4*   preq16   = (uint4*)base;            base += preq_b;
        unsigned long long* packed = (unsigned long long*)base;

        int nwaves = (N + 3) / 4;
        int ewavesP = (E + 63) / 64;
        int total_waves = nwaves + R + B + ewavesP;
        prep_fused16<<<(total_waves + 3) / 4, 256, 0, stream>>>(
            q_rel, query_embed, Wqr_w, Wqr_b, rela_embed, Wr,
            hidden, Ws, edges, hidden16, hs_aux16, hr_h16, hr_aux16, preq16,
            (__half*)agg, packed, N, R, B, E, /*zero_agg=*/1);

        int ewaves = (E + 7) / 8;
        edge_kernel8p<<<(ewaves + 3) / 4, 256, 0, stream>>>(
            packed, hidden16, hr_h16, hs_aux16, hr_aux16, preq16,
            walpha_w, walpha_b, agg, E);

        int ntiles = (N + 63) / 64;
        final_gemm16<<<ntiles, 256, 0, stream>>>(out, (const __half*)agg, Wh, N);
    } else if (f16path) {
        // unlikely fallback: packed buffer doesn't fit; reuse pk kernels via packed==agg trick is unsafe,
        // so fall through to generic f32 path instead.
        float* hs_aux = (float*)d_ws;
        float* hr_h   = hs_aux + (size_t)N * 8;
        float* hr_aux = hr_h + (size_t)R * 64;
        float* preq   = hr_aux + (size_t)R * 8;

        (void)hipMemsetAsync(d_out, 0, (size_t)out_size * sizeof(float), stream);

        int waves_small = R + B;
        prep_small_kernel<<<(waves_small * 64 + 255) / 256, 256, 0, stream>>>(
            q_rel, query_embed, Wqr_w, Wqr_b, rela_embed, Wr,
            hr_h, hr_aux, preq, R, B, A);

        prep_node_kernel<<<(N + 3) / 4, 256, 0, stream>>>(hidden, Ws, hs_aux, N, A);

        edge_kernel_f32<<<(E + 3) / 4, 256, 0, stream>>>(
            edges, hidden, hr_h, hr_aux, hs_aux, preq,
            walpha_w, walpha_b, out, E, A);

        final_kernel_f32<<<1024, 256, 0, stream>>>(out, Wh, N);
    } else {
        float* hs_aux = (float*)d_ws;
        float* hr_h   = hs_aux + (size_t)N * 8;
        float* hr_aux = hr_h + (size_t)R * 64;
        float* preq   = hr_aux + (size_t)R * 8;

        (void)hipMemsetAsync(d_out, 0, (size_t)out_size * sizeof(float), stream);

        int waves_small = R + B;
        prep_small_kernel<<<(waves_small * 64 + 255) / 256, 256, 0, stream>>>(
            q_rel, query_embed, Wqr_w, Wqr_b, rela_embed, Wr,
            hr_h, hr_aux, preq, R, B, A);

        prep_node_kernel<<<(N + 3) / 4, 256, 0, stream>>>(hidden, Ws, hs_aux, N, A);

        edge_kernel_f32<<<(E + 3) / 4, 256, 0, stream>>>(
            edges, hidden, hr_h, hr_aux, hs_aux, preq,
            walpha_w, walpha_b, out, E, A);

        final_kernel_f32<<<1024, 256, 0, stream>>>(out, Wh, N);
    }
}

// Round 13
// 163.162 us; speedup vs baseline: 3.1678x; 3.1678x over previous
//
#include <hip/hip_runtime.h>
#include <hip/hip_bf16.h>
#include <hip/hip_fp16.h>

// Hyperbolic GNN layer. D = 64.
// R13: CSR aggregation, zero atomics on the hot path.
//   prep_fused16  : f16 tables (hidden16, aux, rel, query)
//   scatter_edges : pack edges to 8B, bin by obj>>7 (validated R8-R12)
//   sort_bucket   : counting-sort each bucket by obj&127 -> full obj order;
//                   emit per-node [start,end) offsets
//   csr_edge      : one QUAD (16 lanes) per node; register accumulation over
//                   its sorted edge run; ONE plain store per agg row
//   ovf_edge      : statistical-overflow safety net (global f16 atomics)
//   final_gemm16  : register-GEMM + p_exp/logmap
// Fallbacks: R11 packed-atomic path (157-160us validated), generic f32.

__device__ __forceinline__ float wave_sum(float v) {
#pragma unroll
    for (int off = 32; off > 0; off >>= 1) v += __shfl_xor(v, off, 64);
    return v;
}

// ---- fast HW math ----
__device__ __forceinline__ float frcp(float x) {
#if __has_builtin(__builtin_amdgcn_rcpf)
    return __builtin_amdgcn_rcpf(x);
#else
    return 1.f / x;
#endif
}
__device__ __forceinline__ float fsqrt_(float x) {
#if __has_builtin(__builtin_amdgcn_sqrtf)
    return __builtin_amdgcn_sqrtf(x);
#else
    return sqrtf(x);
#endif
}
__device__ __forceinline__ float flog2_(float x) {
#if __has_builtin(__builtin_amdgcn_logf)
    return __builtin_amdgcn_logf(x);
#else
    return log2f(x);
#endif
}
__device__ __forceinline__ float fexp2_(float x) {
#if __has_builtin(__builtin_amdgcn_exp2f)
    return __builtin_amdgcn_exp2f(x);
#else
    return exp2f(x);
#endif
}
__device__ __forceinline__ float ftanh_pos(float x) {
    return 1.f - 2.f * frcp(fexp2_(x * 2.885390082f) + 1.f);
}

__device__ __forceinline__ unsigned pk2(float a, float b) {
    __half2 h = __floats2half2_rn(a, b);
    return __builtin_bit_cast(unsigned, h);
}
__device__ __forceinline__ float2 upk2(unsigned u) {
    __half2 h = __builtin_bit_cast(__half2, u);
    return __half22float2(h);
}

__device__ __forceinline__ void expmap0_scale(float norm, float& s, float& x2) {
    const float maxn = 1.0f - 0.004f;
    float un = fmaxf(norm, 1e-15f);
    float th = ftanh_pos(fminf(un, 15.0f));
    float gs = th * frcp(un);
    float ng = gs * norm;
    float ps = ng > maxn ? maxn * frcp(ng) : 1.0f;
    s = gs * ps;
    float sn = s * norm;
    x2 = sn * sn;
}

// ================= per-edge math (quad = 16 lanes/edge) =================
// returns (cx, cy): msg = cx*h + cy*y
__device__ __forceinline__ float2 edge_coef(
    unsigned hu_lo, unsigned hu_hi, unsigned yu_lo, unsigned yu_hi,
    uint4 hsa, uint4 hra, uint4 pqa, const float* wa, float wb) {
    float2 hs01 = upk2(hsa.x), hs23 = upk2(hsa.y), hs4 = upk2(hsa.z), hsxs = upk2(hsa.w);
    float2 hr01 = upk2(hra.x), hr23 = upk2(hra.y), hr4 = upk2(hra.z), hry = upk2(hra.w);
    float2 pq01 = upk2(pqa.x), pq23 = upk2(pqa.y), pq4 = upk2(pqa.z);
    float x2 = hsxs.x, s = hsxs.y, y2 = hry.x;

    float2 hl = upk2(hu_lo), hh = upk2(hu_hi);
    float2 yl = upk2(yu_lo), yh = upk2(yu_hi);

    float p = hl.x * yl.x;
    p = fmaf(hl.y, yl.y, p);
    p = fmaf(hh.x, yh.x, p);
    p = fmaf(hh.y, yh.y, p);
    p += __shfl_xor(p, 1, 64);
    p += __shfl_xor(p, 2, 64);
    p += __shfl_xor(p, 4, 64);
    p += __shfl_xor(p, 8, 64);
    float xy = p * s;

    float z = wb;
    z = fmaf(fmaxf(hs01.x + hr01.x + pq01.x, 0.f), wa[0], z);
    z = fmaf(fmaxf(hs01.y + hr01.y + pq01.y, 0.f), wa[1], z);
    z = fmaf(fmaxf(hs23.x + hr23.x + pq23.x, 0.f), wa[2], z);
    z = fmaf(fmaxf(hs23.y + hr23.y + pq23.y, 0.f), wa[3], z);
    z = fmaf(fmaxf(hs4.x + hr4.x + pq4.x, 0.f), wa[4], z);
    float alpha = frcp(1.f + fexp2_(z * -1.44269504f));

    float Af  = 1.f + 2.f * xy + y2;
    float Bf  = 1.f - x2;
    float den = fmaxf(1.f + 2.f * xy + x2 * y2, 1e-15f);
    float inv = frcp(den);
    float nm2 = fmaxf(fmaf(Af * Af, x2, fmaf(2.f * Af * Bf, xy, Bf * Bf * y2)), 0.f);
    float nm  = fsqrt_(nm2) * inv;
    const float maxn = 1.0f - 0.004f;
    float ps  = nm > maxn ? maxn * frcp(nm) : 1.f;
    float yn  = fmaxf(fminf(nm, maxn), 1e-15f);
    float ratio = (1.f + yn) * frcp(1.f - yn);
    float art = 0.34657359f * flog2_(ratio);
    float k  = inv * ps * alpha * art * frcp(yn);
    return make_float2(k * Af * s, k * Bf);
}

__device__ __forceinline__ void edge_to_global(
    unsigned hu_lo, unsigned hu_hi, unsigned yu_lo, unsigned yu_hi,
    uint4 hsa, uint4 hra, uint4 pqa, const float* wa, float wb,
    bool act, __half2* dst /* agg + obj*32 + j */) {
    float2 c = edge_coef(hu_lo, hu_hi, yu_lo, yu_hi, hsa, hra, pqa, wa, wb);
    float2 hl = upk2(hu_lo), hh = upk2(hu_hi);
    float2 yl = upk2(yu_lo), yh = upk2(yu_hi);
    __half2 q_lo = __floats2half2_rn(fmaf(c.x, hl.x, c.y * yl.x), fmaf(c.x, hl.y, c.y * yl.y));
    __half2 q_hi = __floats2half2_rn(fmaf(c.x, hh.x, c.y * yh.x), fmaf(c.x, hh.y, c.y * yh.y));
    if (act) {
        unsafeAtomicAdd(dst, q_lo);
        unsafeAtomicAdd(dst + 16, q_hi);
    }
}

// ================= prep (+ optional edge packing for fallback path) ==========
__global__ void prep_fused16(const int* __restrict__ q_rel,
                             const float* __restrict__ query_embed,
                             const float* __restrict__ Wqr_w,
                             const float* __restrict__ Wqr_b,
                             const float* __restrict__ rela_embed,
                             const float* __restrict__ Wr,
                             const float* __restrict__ hidden,
                             const float* __restrict__ Ws,
                             const int* __restrict__ edges,
                             __half* __restrict__ hidden16,
                             uint4* __restrict__ hs_aux16,
                             __half* __restrict__ hr_h16,
                             uint4* __restrict__ hr_aux16,
                             uint4* __restrict__ preq16,
                             __half* __restrict__ agg16,
                             unsigned long long* __restrict__ packed,
                             int N, int R, int B, int E, int zero_agg) {
    int wid = (blockIdx.x * blockDim.x + threadIdx.x) >> 6;
    int lane = threadIdx.x & 63;
    int nwaves = (N + 3) >> 2;
    if (wid < nwaves) {
        int q = lane >> 4, j = lane & 15;
        int n = wid * 4 + q;
        bool act = n < N;
        int nc = act ? n : N - 1;

        float4 u = *(const float4*)(hidden + (size_t)nc * 64 + 4 * j);
        float4 w0 = *(const float4*)(Ws + 0 * 64 + 4 * j);
        float4 w1 = *(const float4*)(Ws + 1 * 64 + 4 * j);
        float4 w2 = *(const float4*)(Ws + 2 * 64 + 4 * j);
        float4 w3 = *(const float4*)(Ws + 3 * 64 + 4 * j);
        float4 w4 = *(const float4*)(Ws + 4 * 64 + 4 * j);

#define DOT4(a, b) (fmaf((a).x, (b).x, fmaf((a).y, (b).y, fmaf((a).z, (b).z, (a).w * (b).w))))
        float p0 = DOT4(u, u);
        float p1 = DOT4(u, w0);
        float p2 = DOT4(u, w1);
        float p3 = DOT4(u, w2);
        float p4 = DOT4(u, w3);
        float p5 = DOT4(u, w4);
#undef DOT4
#pragma unroll
        for (int off = 1; off < 16; off <<= 1) {
            p0 += __shfl_xor(p0, off, 64);
            p1 += __shfl_xor(p1, off, 64);
            p2 += __shfl_xor(p2, off, 64);
            p3 += __shfl_xor(p3, off, 64);
            p4 += __shfl_xor(p4, off, 64);
            p5 += __shfl_xor(p5, off, 64);
        }
        float s, x2;
        expmap0_scale(fsqrt_(p0), s, x2);
        if (act) {
            uint2 hp; hp.x = pk2(u.x, u.y); hp.y = pk2(u.z, u.w);
            *(uint2*)(hidden16 + (size_t)n * 64 + 4 * j) = hp;
            if (zero_agg) {
                uint2 zz; zz.x = 0u; zz.y = 0u;
                ((uint2*)(agg16 + (size_t)n * 64))[j] = zz;
            }
            if (j == 0) {
                uint4 o; o.x = pk2(p1, p2); o.y = pk2(p3, p4); o.z = pk2(p5, 0.f); o.w = pk2(x2, s);
                hs_aux16[n] = o;
            }
        }
        return;
    }
    int w2 = wid - nwaves;
    if (w2 < R) {
        int r = w2;
        float u = rela_embed[r * 64 + lane];
        float p0 = u * u;
        float p1 = u * Wr[0 * 64 + lane];
        float p2 = u * Wr[1 * 64 + lane];
        float p3 = u * Wr[2 * 64 + lane];
        float p4 = u * Wr[3 * 64 + lane];
        float p5 = u * Wr[4 * 64 + lane];
#pragma unroll
        for (int off = 1; off < 64; off <<= 1) {
            p0 += __shfl_xor(p0, off, 64);
            p1 += __shfl_xor(p1, off, 64);
            p2 += __shfl_xor(p2, off, 64);
            p3 += __shfl_xor(p3, off, 64);
            p4 += __shfl_xor(p4, off, 64);
            p5 += __shfl_xor(p5, off, 64);
        }
        float s, y2;
        expmap0_scale(fsqrt_(p0), s, y2);
        hr_h16[r * 64 + lane] = __float2half(s * u);
        if (lane == 0) {
            uint4 o; o.x = pk2(p1, p2); o.y = pk2(p3, p4); o.z = pk2(p5, 0.f); o.w = pk2(y2, 0.f);
            hr_aux16[r] = o;
        }
        return;
    }
    int w3 = w2 - R;
    if (w3 < B) {
        int b = w3;
        int qr = q_rel[b];
        float q = query_embed[qr * 64 + lane];
        float p1 = q * Wqr_w[0 * 64 + lane];
        float p2 = q * Wqr_w[1 * 64 + lane];
        float p3 = q * Wqr_w[2 * 64 + lane];
        float p4 = q * Wqr_w[3 * 64 + lane];
        float p5 = q * Wqr_w[4 * 64 + lane];
#pragma unroll
        for (int off = 1; off < 64; off <<= 1) {
            p1 += __shfl_xor(p1, off, 64);
            p2 += __shfl_xor(p2, off, 64);
            p3 += __shfl_xor(p3, off, 64);
            p4 += __shfl_xor(p4, off, 64);
            p5 += __shfl_xor(p5, off, 64);
        }
        if (lane == 0) {
            uint4 o;
            o.x = pk2(p1 + Wqr_b[0], p2 + Wqr_b[1]);
            o.y = pk2(p3 + Wqr_b[2], p4 + Wqr_b[3]);
            o.z = pk2(p5 + Wqr_b[4], 0.f);
            o.w = pk2(0.f, 0.f);
            preq16[b] = o;
        }
        return;
    }
    // optional edge packing (fallback path only; E==0 on CSR path)
    int w4 = w3 - B;
    int e = w4 * 64 + lane;
    if (e < E) {
        const int* er = edges + (size_t)e * 6;
        int ri  = er[0];
        int rel = er[2];
        int sub = er[4];
        int obj = er[5];
        unsigned long long pk = (unsigned long long)(unsigned)(obj & 0x1ffff)
            | ((unsigned long long)(unsigned)(sub & 0x1ffff) << 17)
            | ((unsigned long long)(unsigned)(rel & 0x1ff) << 34)
            | ((unsigned long long)(unsigned)(ri & 0x1ff) << 43);
        __builtin_nontemporal_store(pk, &packed[e]);
    }
}

// ================= CSR build =================

__global__ void init_cur(int* __restrict__ cur, int NB, int cap) {
    int i = blockIdx.x * blockDim.x + threadIdx.x;
    if (i < NB) cur[i] = i * cap;
    else if (i == NB) cur[i] = 0;   // overflow counter
}

// pack + bin edges by obj>>7. 4096 edges/block. (validated R8-R12)
__global__ __launch_bounds__(256) void scatter_edges(
    const int* __restrict__ edges, int E, int NB, int cap,
    int* __restrict__ cur,
    unsigned long long* __restrict__ bbuf,
    unsigned long long* __restrict__ ovfbuf, int ovfcap)
{
    __shared__ unsigned long long spk[4096];
    __shared__ int lh[1024];
    __shared__ int lb[1024];
    int t = threadIdx.x;
    int base = blockIdx.x * 4096;
    for (int i = t; i < NB; i += 256) lh[i] = 0;
    __syncthreads();
    int nloc = min(4096, E - base);
    for (int k = t; k < nloc; k += 256) {
        const long long* er = (const long long*)(edges + (size_t)(base + k) * 6);
        long long a = er[0], bq = er[1], cq = er[2];
        int ri = (int)a, rel = (int)bq, sub = (int)cq, obj = (int)(cq >> 32);
        unsigned long long pk = (unsigned long long)(unsigned)(obj & 0x1ffff)
            | ((unsigned long long)(unsigned)(sub & 0x1ffff) << 17)
            | ((unsigned long long)(unsigned)(rel & 0x1ff) << 34)
            | ((unsigned long long)(unsigned)(ri & 0x1ff) << 43);
        spk[k] = pk;
        atomicAdd(&lh[obj >> 7], 1);
    }
    __syncthreads();
    for (int i = t; i < NB; i += 256) {
        int c = lh[i];
        lb[i] = c ? atomicAdd(&cur[i], c) : 0;
    }
    __syncthreads();
    for (int i = t; i < NB; i += 256) lh[i] = 0;
    __syncthreads();
    for (int k = t; k < nloc; k += 256) {
        unsigned long long pk = spk[k];
        int bk = (int)(pk & 0x1ffff) >> 7;
        int rank = atomicAdd(&lh[bk], 1);
        int slot = lb[bk] + rank;
        if (slot < (bk + 1) * cap) {
            bbuf[slot] = pk;
        } else {
            int o = atomicAdd(cur + NB, 1);
            if (o < ovfcap) ovfbuf[o] = pk;
        }
    }
}

// counting-sort each bucket by obj&127 -> full obj order; emit node offsets.
__global__ __launch_bounds__(256) void sort_bucket(
    unsigned long long* __restrict__ bbuf,
    const int* __restrict__ cur, int cap,
    int2* __restrict__ nodeoff)   // [NB*128]: per-node (start,end) into bbuf
{
    __shared__ unsigned long long spk[4096];   // cap <= 4096 guarded on host
    __shared__ int hist[128];
    __shared__ int pfx[129];
    __shared__ int rk[128];
    int b = blockIdx.x;
    int t = threadIdx.x;
    int start = b * cap;
    int cnt = cur[b] - start;
    if (cnt < 0) cnt = 0;
    if (cnt > cap) cnt = cap;
    if (t < 128) { hist[t] = 0; rk[t] = 0; }
    __syncthreads();
    for (int i = t; i < cnt; i += 256) {
        unsigned long long pk = bbuf[start + i];
        spk[i] = pk;
        atomicAdd(&hist[(int)(pk & 127)], 1);
    }
    __syncthreads();
    if (t == 0) {
        int acc = 0;
#pragma unroll 4
        for (int i = 0; i < 128; ++i) { pfx[i] = acc; acc += hist[i]; }
        pfx[128] = acc;
    }
    __syncthreads();
    if (t < 128) {
        nodeoff[b * 128 + t] = make_int2(start + pfx[t], start + pfx[t + 1]);
    }
    for (int i = t; i < cnt; i += 256) {
        unsigned long long pk = spk[i];
        int loc = (int)(pk & 127);
        int r = atomicAdd(&rk[loc], 1);
        bbuf[start + pfx[loc] + r] = pk;
    }
}

// one quad (16 lanes) per node: register-accumulate its edge run, one store.
__global__ __launch_bounds__(256) void csr_edge(
    const unsigned long long* __restrict__ bbuf,
    const int2* __restrict__ nodeoff,
    const __half* __restrict__ hidden16,
    const __half* __restrict__ hr_h16,
    const uint4* __restrict__ hs_aux16,
    const uint4* __restrict__ hr_aux16,
    const uint4* __restrict__ preq16,
    const float* __restrict__ walpha_w,
    const float* __restrict__ walpha_b,
    __half* __restrict__ agg16,
    int N, int Ntot)
{
    int t = threadIdx.x;
    int lane = t & 63;
    int g = lane >> 4;
    int j = lane & 15;
    int node = blockIdx.x * 16 + (t >> 6) * 4 + g;
    if (node >= Ntot) return;

    float wa[5];
    wa[0] = walpha_w[0]; wa[1] = walpha_w[1]; wa[2] = walpha_w[2];
    wa[3] = walpha_w[3]; wa[4] = walpha_w[4];
    float wb = walpha_b[0];

    int2 off = nodeoff[node];
    float a0 = 0.f, a1 = 0.f, a2 = 0.f, a3 = 0.f;
    for (int e = off.x; e < off.y; ++e) {
        unsigned long long pk = bbuf[e];           // quad-uniform -> broadcast
        int sub = (int)((pk >> 17) & 0x1ffff);
        int rel = (int)((pk >> 34) & 0x1ff);
        int ri  = (int)((pk >> 43) & 0x1ff);
        uint4 hsa = hs_aux16[sub], hra = hr_aux16[rel], pqa = preq16[ri];
        const unsigned* hrow = (const unsigned*)(hidden16 + (size_t)sub * 64);
        const unsigned* yrow = (const unsigned*)(hr_h16 + (size_t)rel * 64);
        unsigned hu_lo = hrow[j], hu_hi = hrow[16 + j];
        unsigned yu_lo = yrow[j], yu_hi = yrow[16 + j];
        float2 c = edge_coef(hu_lo, hu_hi, yu_lo, yu_hi, hsa, hra, pqa, wa, wb);
        float2 hl = upk2(hu_lo), hh = upk2(hu_hi);
        float2 yl = upk2(yu_lo), yh = upk2(yu_hi);
        a0 = fmaf(c.x, hl.x, fmaf(c.y, yl.x, a0));
        a1 = fmaf(c.x, hl.y, fmaf(c.y, yl.y, a1));
        a2 = fmaf(c.x, hh.x, fmaf(c.y, yh.x, a2));
        a3 = fmaf(c.x, hh.y, fmaf(c.y, yh.y, a3));
    }
    if (node < N) {
        unsigned* dst = (unsigned*)(agg16 + (size_t)node * 64);
        __builtin_nontemporal_store(pk2(a0, a1), dst + j);
        __builtin_nontemporal_store(pk2(a2, a3), dst + 16 + j);
    }
}

// overflow edges (expected none): global f16 atomics ON TOP of csr rows
__global__ __launch_bounds__(256) void ovf_edge(
    const unsigned long long* __restrict__ ovfbuf,
    const int* __restrict__ ovfcnt_p, int ovfcap,
    const __half* __restrict__ hidden16,
    const __half* __restrict__ hr_h16,
    const uint4* __restrict__ hs_aux16,
    const uint4* __restrict__ hr_aux16,
    const uint4* __restrict__ preq16,
    const float* __restrict__ walpha_w,
    const float* __restrict__ walpha_b,
    __half2* __restrict__ agg)
{
    int cnt = min(*ovfcnt_p, ovfcap);
    if (cnt <= 0) return;
    int j = threadIdx.x & 15;
    int qid = (blockIdx.x * blockDim.x + threadIdx.x) >> 4;
    int nq = (gridDim.x * blockDim.x) >> 4;
    float wa[5];
    wa[0] = walpha_w[0]; wa[1] = walpha_w[1]; wa[2] = walpha_w[2];
    wa[3] = walpha_w[3]; wa[4] = walpha_w[4];
    float wb = walpha_b[0];
    for (int e = qid; e < cnt; e += nq) {
        unsigned long long pk = ovfbuf[e];
        int obj = (int)(pk & 0x1ffff), sub = (int)((pk >> 17) & 0x1ffff);
        int rel = (int)((pk >> 34) & 0x1ff), ri = (int)((pk >> 43) & 0x1ff);
        uint4 hsa = hs_aux16[sub], hra = hr_aux16[rel], pqa = preq16[ri];
        const unsigned* hrow = (const unsigned*)(hidden16 + (size_t)sub * 64);
        const unsigned* yrow = (const unsigned*)(hr_h16 + (size_t)rel * 64);
        edge_to_global(hrow[j], hrow[16 + j], yrow[j], yrow[16 + j],
                       hsa, hra, pqa, wa, wb, true, agg + (size_t)obj * 32 + j);
    }
}

// ================= R11 fallback edge kernel (packed, atomic) =================
__global__ __launch_bounds__(256) void edge_kernel8p(
    const unsigned long long* __restrict__ packed,
    const __half* __restrict__ hidden16,
    const __half* __restrict__ hr_h16,
    const uint4* __restrict__ hs_aux16,
    const uint4* __restrict__ hr_aux16,
    const uint4* __restrict__ preq16,
    const float* __restrict__ walpha_w,
    const float* __restrict__ walpha_b,
    __half2* __restrict__ agg,
    int E)
{
    int wid = (blockIdx.x * blockDim.x + threadIdx.x) >> 6;
    int lane = threadIdx.x & 63;
    int g = lane >> 4;
    int j = lane & 15;

    int e0 = wid * 8 + g;
    int e1 = wid * 8 + 4 + g;
    bool act0 = e0 < E, act1 = e1 < E;

    unsigned long long p0 = __builtin_nontemporal_load(&packed[act0 ? e0 : 0]);
    unsigned long long p1 = __builtin_nontemporal_load(&packed[act1 ? e1 : 0]);
    int obj0 = (int)(p0 & 0x1ffff), sub0 = (int)((p0 >> 17) & 0x1ffff);
    int rel0 = (int)((p0 >> 34) & 0x1ff), r0 = (int)((p0 >> 43) & 0x1ff);
    int obj1 = (int)(p1 & 0x1ffff), sub1 = (int)((p1 >> 17) & 0x1ffff);
    int rel1 = (int)((p1 >> 34) & 0x1ff), r1 = (int)((p1 >> 43) & 0x1ff);

    uint4 hsa0 = hs_aux16[sub0], hra0 = hr_aux16[rel0], pqa0 = preq16[r0];
    uint4 hsa1 = hs_aux16[sub1], hra1 = hr_aux16[rel1], pqa1 = preq16[r1];

    const unsigned* hrow0 = (const unsigned*)(hidden16 + (size_t)sub0 * 64);
    const unsigned* yrow0 = (const unsigned*)(hr_h16 + (size_t)rel0 * 64);
    const unsigned* hrow1 = (const unsigned*)(hidden16 + (size_t)sub1 * 64);
    const unsigned* yrow1 = (const unsigned*)(hr_h16 + (size_t)rel1 * 64);

    float wa[5];
    wa[0] = walpha_w[0]; wa[1] = walpha_w[1]; wa[2] = walpha_w[2];
    wa[3] = walpha_w[3]; wa[4] = walpha_w[4];
    float wb = walpha_b[0];

    edge_to_global(hrow0[j], hrow0[16 + j], yrow0[j], yrow0[16 + j],
                   hsa0, hra0, pqa0, wa, wb, act0, agg + (size_t)obj0 * 32 + j);
    edge_to_global(hrow1[j], hrow1[16 + j], yrow1[j], yrow1[16 + j],
                   hsa1, hra1, pqa1, wa, wb, act1, agg + (size_t)obj1 * 32 + j);
}

// ================= final: one 64-row tile per block =================
__global__ __launch_bounds__(256) void final_gemm16(
    float* __restrict__ out,
    const __half* __restrict__ agg16,
    const float* __restrict__ Wh,
    int N)
{
    __shared__ __half tile[64 * 64];
    int t = threadIdx.x;
    int lane = t & 63;
    int w = t >> 6;

    float wh[64];
    const float4* whr = (const float4*)(Wh + (size_t)lane * 64);
#pragma unroll
    for (int i = 0; i < 16; ++i) {
        float4 v = whr[i];
        wh[4 * i] = v.x; wh[4 * i + 1] = v.y; wh[4 * i + 2] = v.z; wh[4 * i + 3] = v.w;
    }

    int base = blockIdx.x << 6;
    int nrow = min(64, N - base);
    {
        const uint2* src = (const uint2*)(agg16 + (size_t)base * 64);
        uint2* dst = (uint2*)tile;
        int nu2 = nrow * 16;
        for (int i = t; i < nu2; i += 256) dst[i] = src[i];
    }
    __syncthreads();

#pragma unroll 1
    for (int r = 0; r < 16; ++r) {
        int n = base + w * 16 + r;
        if (n >= N) break;
        const uint2* arow = (const uint2*)(tile + (w * 16 + r) * 64);
        float acc = 0.f;
#pragma unroll
        for (int kk = 0; kk < 16; ++kk) {
            uint2 u = arow[kk];
            float2 f0 = upk2(u.x), f1 = upk2(u.y);
            acc = fmaf(f0.x, wh[4 * kk], acc);
            acc = fmaf(f0.y, wh[4 * kk + 1], acc);
            acc = fmaf(f1.x, wh[4 * kk + 2], acc);
            acc = fmaf(f1.y, wh[4 * kk + 3], acc);
        }
        float n2 = wave_sum(acc * acc);
        float na = fsqrt_(n2);
        float nv = fmaxf(na, 1e-10f);
        float pn = ftanh_pos(nv);
        float rinv = frcp(nv);
        float pp = pn * acc * rinv;
        float np = pn * (na * rinv);
        float yn = fmaxf(np, 1e-15f);
        float tt = fminf(yn, 1.f - 1e-5f);
        float ratio = (1.f + tt) * frcp(1.f - tt);
        float art = 0.34657359f * flog2_(ratio);
        __builtin_nontemporal_store(pp * art * frcp(yn), &out[(size_t)n * 64 + lane]);
    }
}

// ================= generic fallback (any A, f32) =================

__global__ void prep_small_kernel(const int* __restrict__ q_rel,
                                  const float* __restrict__ query_embed,
                                  const float* __restrict__ Wqr_w,
                                  const float* __restrict__ Wqr_b,
                                  const float* __restrict__ rela_embed,
                                  const float* __restrict__ Wr,
                                  float* __restrict__ hr_h,
                                  float* __restrict__ hr_aux,
                                  float* __restrict__ preq,
                                  int R, int B, int A) {
    int w = (blockIdx.x * blockDim.x + threadIdx.x) >> 6;
    int lane = threadIdx.x & 63;
    if (w < R) {
        int r = w;
        float u = rela_embed[r * 64 + lane];
        float n2 = wave_sum(u * u);
        float s, y2;
        expmap0_scale(fsqrt_(n2), s, y2);
        hr_h[r * 64 + lane] = s * u;
        for (int a = 0; a < A; ++a) {
            float p = wave_sum(u * Wr[a * 64 + lane]);
            if (lane == 0) hr_aux[r * 8 + a] = p;
        }
        if (lane == 0) hr_aux[r * 8 + 6] = y2;
    } else if (w < R + B) {
        int b = w - R;
        int qr = q_rel[b];
        float q = query_embed[qr * 64 + lane];
        for (int a = 0; a < A; ++a) {
            float p = wave_sum(q * Wqr_w[a * 64 + lane]);
            if (lane == 0) preq[b * 8 + a] = p + Wqr_b[a];
        }
    }
}

__global__ void prep_node_kernel(const float* __restrict__ hidden,
                                 const float* __restrict__ Ws,
                                 float* __restrict__ hs_aux, int N, int A) {
    int w = (blockIdx.x * blockDim.x + threadIdx.x) >> 6;
    if (w >= N) return;
    int lane = threadIdx.x & 63;
    float u = hidden[(size_t)w * 64 + lane];
    float n2 = wave_sum(u * u);
    float s, x2;
    expmap0_scale(fsqrt_(n2), s, x2);
    for (int a = 0; a < A; ++a) {
        float p = wave_sum(u * Ws[a * 64 + lane]);
        if (lane == 0) hs_aux[w * 8 + a] = p;
    }
    if (lane == 0) { hs_aux[w * 8 + 6] = x2; hs_aux[w * 8 + 7] = s; }
}

__global__ void edge_kernel_f32(const int* __restrict__ edges,
                                const float* __restrict__ hidden,
                                const float* __restrict__ hr_h,
                                const float* __restrict__ hr_aux,
                                const float* __restrict__ hs_aux,
                                const float* __restrict__ preq,
                                const float* __restrict__ walpha_w,
                                const float* __restrict__ walpha_b,
                                float* __restrict__ agg,
                                int E, int A) {
    int w = (blockIdx.x * blockDim.x + threadIdx.x) >> 6;
    if (w >= E) return;
    int lane = threadIdx.x & 63;
    const int* er = edges + (size_t)w * 6;
    int r_idx = er[0], rel = er[2], sub = er[4], obj = er[5];

    float s  = hs_aux[(size_t)sub * 8 + 7];
    float x2 = hs_aux[(size_t)sub * 8 + 6];
    float h  = hidden[(size_t)sub * 64 + lane];
    float x  = h * s;
    float y  = hr_h[(size_t)rel * 64 + lane];
    float y2 = hr_aux[(size_t)rel * 8 + 6];
    float xy = wave_sum(x * y);

    float z = walpha_b[0];
    for (int a = 0; a < A; ++a) {
        float pre = hs_aux[(size_t)sub * 8 + a] + hr_aux[(size_t)rel * 8 + a] + preq[(size_t)r_idx * 8 + a];
        z += fmaxf(pre, 0.f) * walpha_w[a];
    }
    float alpha = frcp(1.f + fexp2_(z * -1.44269504f));

    float Af = 1.f + 2.f * xy + y2;
    float Bf = 1.f - x2;
    float den = fmaxf(1.f + 2.f * xy + x2 * y2, 1e-15f);
    float inv = frcp(den);
    float nm2 = fmaxf(Af * Af * x2 + 2.f * Af * Bf * xy + Bf * Bf * y2, 0.f);
    float nm = fsqrt_(nm2) * inv;
    const float maxn = 1.0f - 0.004f;
    float ps = nm > maxn ? maxn * frcp(nm) : 1.f;
    float yn = fmaxf(fminf(nm, maxn), 1e-15f);
    float ratio = (1.f + yn) * frcp(1.f - yn);
    float art = 0.34657359f * flog2_(ratio);
    float k = inv * ps * alpha * art * frcp(yn);
    float msg = fmaf(k * Af * s, h, k * Bf * y);
    unsafeAtomicAdd(agg + (size_t)obj * 64 + lane, msg);
}

__global__ void final_kernel_f32(float* __restrict__ out,
                                 const float* __restrict__ Wh,
                                 int N) {
    __shared__ float WhT[64 * 64];
    int t = threadIdx.x;
    for (int i = t; i < 64 * 64; i += blockDim.x) {
        int row = i >> 6, col = i & 63;
        WhT[col * 64 + row] = Wh[i];
    }
    __syncthreads();

    int lane = t & 63;
    int wl = t >> 6;
    int wpb = blockDim.x >> 6;
    int wg = blockIdx.x * wpb + wl;
    int wstride = gridDim.x * wpb;

    for (int n = wg; n < N; n += wstride) {
        float v = out[(size_t)n * 64 + lane];
        float a = 0.f;
#pragma unroll
        for (int k = 0; k < 64; ++k)
            a = fmaf(__shfl(v, k, 64), WhT[k * 64 + lane], a);

        float n2 = wave_sum(a * a);
        float na = fsqrt_(n2);
        float nv = fmaxf(na, 1e-10f);
        float pn = tanhf(nv);
        float rinv = frcp(nv);
        float pp = pn * a * rinv;
        float np = pn * (na * rinv);
        float yn = fmaxf(np, 1e-15f);
        float tt = fminf(yn, 1.f - 1e-5f);
        float ratio = (1.f + tt) * frcp(1.f - tt);
        float art = 0.34657359f * flog2_(ratio);
        out[(size_t)n * 64 + lane] = pp * art * frcp(yn);
    }
}

extern "C" void kernel_launch(void* const* d_in, const int* in_sizes, int n_in,
                              void* d_out, int out_size, void* d_ws, size_t ws_size,
                              hipStream_t stream) {
    const int*   q_rel       = (const int*)d_in[1];
    const float* hidden      = (const float*)d_in[2];
    const int*   edges       = (const int*)d_in[3];
    const float* rela_embed  = (const float*)d_in[6];
    const float* query_embed = (const float*)d_in[7];
    const float* Ws          = (const float*)d_in[8];
    const float* Wr          = (const float*)d_in[9];
    const float* Wqr_w       = (const float*)d_in[10];
    const float* Wqr_b       = (const float*)d_in[11];
    const float* walpha_w    = (const float*)d_in[12];
    const float* walpha_b    = (const float*)d_in[13];
    const float* Wh          = (const float*)d_in[14];

    const int D = 64;
    int B = in_sizes[0];
    int E = in_sizes[3] / 6;
    int A = in_sizes[11];
    int R = in_sizes[6] / D;
    int N = out_size / D;

    float* out = (float*)d_out;

    size_t agg_b    = (size_t)N * 128;
    size_t hid16_b  = (size_t)N * 128;
    size_t hsaux_b  = (size_t)N * 16;
    size_t hrh_b    = (size_t)R * 128;
    size_t hraux_b  = (size_t)R * 16;
    size_t preq_b   = (size_t)B * 16;
    size_t need16   = agg_b + hid16_b + hsaux_b + hrh_b + hraux_b + preq_b;
    size_t packed_b = (size_t)E * 8;
    size_t need_pk  = need16 + packed_b;

    int NB = (N + 127) >> 7;
    int Ntot = NB * 128;
    int cap = (NB > 0) ? 2 * ((E + NB - 1) / NB) : 512;
    if (cap < 512) cap = 512;
    int ovfcap = 65536;
    size_t bbuf_b = (size_t)NB * (size_t)cap * 8;
    size_t cur_b  = (((size_t)NB + 1) * 4 + 15) & ~(size_t)15;
    size_t noff_b = (size_t)Ntot * 8;
    size_t ovf_b  = (size_t)ovfcap * 8;
    size_t need_csr = need16 + bbuf_b + cur_b + noff_b + ovf_b;

    bool fields_ok = (N > 0) && (N <= 131072) && (R <= 512) && (B <= 512);
    bool csr_ok = (A == 5) && fields_ok && (NB <= 1024) && (E > 0) &&
                  (cap <= 4096) && ((long long)NB * cap < (1LL << 31)) &&
                  (ws_size >= need_csr);
    bool pkpath = (A == 5) && fields_ok && (ws_size >= need_pk);

    if (csr_ok) {
        char* base = (char*)d_ws;
        __half* agg16    = (__half*)base;            base += agg_b;
        __half* hidden16 = (__half*)base;            base += hid16_b;
        uint4*  hs_aux16 = (uint4*)base;             base += hsaux_b;
        __half* hr_h16   = (__half*)base;            base += hrh_b;
        uint4*  hr_aux16 = (uint4*)base;             base += hraux_b;
        uint4*  preq16   = (uint4*)base;             base += preq_b;
        unsigned long long* bbuf = (unsigned long long*)base; base += bbuf_b;
        int* cur = (int*)base;                       base += cur_b;
        int2* nodeoff = (int2*)base;                 base += noff_b;
        unsigned long long* ovfbuf = (unsigned long long*)base;

        init_cur<<<(NB + 1 + 255) / 256, 256, 0, stream>>>(cur, NB, cap);

        int nwaves = (N + 3) / 4;
        int total_waves = nwaves + R + B;
        prep_fused16<<<(total_waves + 3) / 4, 256, 0, stream>>>(
            q_rel, query_embed, Wqr_w, Wqr_b, rela_embed, Wr,
            hidden, Ws, edges, hidden16, hs_aux16, hr_h16, hr_aux16, preq16,
            agg16, (unsigned long long*)nullptr, N, R, B, 0, /*zero_agg=*/0);

        scatter_edges<<<(E + 4095) / 4096, 256, 0, stream>>>(
            edges, E, NB, cap, cur, bbuf, ovfbuf, ovfcap);

        sort_bucket<<<NB, 256, 0, stream>>>(bbuf, cur, cap, nodeoff);

        csr_edge<<<(Ntot + 15) / 16, 256, 0, stream>>>(
            bbuf, nodeoff, hidden16, hr_h16, hs_aux16, hr_aux16, preq16,
            walpha_w, walpha_b, agg16, N, Ntot);

        ovf_edge<<<64, 256, 0, stream>>>(
            ovfbuf, cur + NB, ovfcap, hidden16, hr_h16, hs_aux16, hr_aux16,
            preq16, walpha_w, walpha_b, (__half2*)agg16);

        int ntiles = (N + 63) / 64;
        final_gemm16<<<ntiles, 256, 0, stream>>>(out, agg16, Wh, N);
    } else if (pkpath) {
        char* base = (char*)d_ws;
        __half2* agg      = (__half2*)base;          base += agg_b;
        __half*  hidden16 = (__half*)base;           base += hid16_b;
        uint4*   hs_aux16 = (uint4*)base;            base += hsaux_b;
        __half*  hr_h16   = (__half*)base;           base += hrh_b;
        uint4*   hr_aux16 = (uint4*)base;            base += hraux_b;
        uint4*   preq16   = (uint4*)base;            base += preq_b;
        unsigned long long* packed = (unsigned long long*)base;

        int nwaves = (N + 3) / 4;
        int ewavesP = (E + 63) / 64;
        int total_waves = nwaves + R + B + ewavesP;
        prep_fused16<<<(total_waves + 3) / 4, 256, 0, stream>>>(
            q_rel, query_embed, Wqr_w, Wqr_b, rela_embed, Wr,
            hidden, Ws, edges, hidden16, hs_aux16, hr_h16, hr_aux16, preq16,
            (__half*)agg, packed, N, R, B, E, /*zero_agg=*/1);

        int ewaves = (E + 7) / 8;
        edge_kernel8p<<<(ewaves + 3) / 4, 256, 0, stream>>>(
            packed, hidden16, hr_h16, hs_aux16, hr_aux16, preq16,
            walpha_w, walpha_b, agg, E);

        int ntiles = (N + 63) / 64;
        final_gemm16<<<ntiles, 256, 0, stream>>>(out, (const __half*)agg, Wh, N);
    } else {
        float* hs_aux = (float*)d_ws;
        float* hr_h   = hs_aux + (size_t)N * 8;
        float* hr_aux = hr_h + (size_t)R * 64;
        float* preq   = hr_aux + (size_t)R * 8;

        (void)hipMemsetAsync(d_out, 0, (size_t)out_size * sizeof(float), stream);

        int waves_small = R + B;
        prep_small_kernel<<<(waves_small * 64 + 255) / 256, 256, 0, stream>>>(
            q_rel, query_embed, Wqr_w, Wqr_b, rela_embed, Wr,
            hr_h, hr_aux, preq, R, B, A);

        prep_node_kernel<<<(N + 3) / 4, 256, 0, stream>>>(hidden, Ws, hs_aux, N, A);

        edge_kernel_f32<<<(E + 3) / 4, 256, 0, stream>>>(
            edges, hidden, hr_h, hr_aux, hs_aux, preq,
            walpha_w, walpha_b, out, E, A);

        final_kernel_f32<<<1024, 256, 0, stream>>>(out, Wh, N);
    }
}

// Round 14
// 156.984 us; speedup vs baseline: 3.2925x; 1.0394x over previous
//
#include <hip/hip_runtime.h>
#include <hip/hip_bf16.h>
#include <hip/hip_fp16.h>

// Hyperbolic GNN layer. D = 64.
// R14: CSR aggregation (zero atomics), VALU-optimized:
//   - f32 aux tables (no per-edge f16->f32 cvt for the uniform chain)
//   - wave-per-node csr_edge (4 edges/iter, cross-quad reduce; no divergence)
//   - init_cur folded into prep
// Pipeline: prep_fused16 -> scatter_edges -> sort_bucket -> csr_edge_w
//           -> ovf_edge -> final_gemm16
// Fallbacks: R11 packed-atomic path, generic f32 path.

__device__ __forceinline__ float wave_sum(float v) {
#pragma unroll
    for (int off = 32; off > 0; off >>= 1) v += __shfl_xor(v, off, 64);
    return v;
}

// ---- fast HW math ----
__device__ __forceinline__ float frcp(float x) {
#if __has_builtin(__builtin_amdgcn_rcpf)
    return __builtin_amdgcn_rcpf(x);
#else
    return 1.f / x;
#endif
}
__device__ __forceinline__ float fsqrt_(float x) {
#if __has_builtin(__builtin_amdgcn_sqrtf)
    return __builtin_amdgcn_sqrtf(x);
#else
    return sqrtf(x);
#endif
}
__device__ __forceinline__ float flog2_(float x) {
#if __has_builtin(__builtin_amdgcn_logf)
    return __builtin_amdgcn_logf(x);
#else
    return log2f(x);
#endif
}
__device__ __forceinline__ float fexp2_(float x) {
#if __has_builtin(__builtin_amdgcn_exp2f)
    return __builtin_amdgcn_exp2f(x);
#else
    return exp2f(x);
#endif
}
__device__ __forceinline__ float ftanh_pos(float x) {
    return 1.f - 2.f * frcp(fexp2_(x * 2.885390082f) + 1.f);
}

__device__ __forceinline__ unsigned pk2(float a, float b) {
    __half2 h = __floats2half2_rn(a, b);
    return __builtin_bit_cast(unsigned, h);
}
__device__ __forceinline__ float2 upk2(unsigned u) {
    __half2 h = __builtin_bit_cast(__half2, u);
    return __half22float2(h);
}

__device__ __forceinline__ void expmap0_scale(float norm, float& s, float& x2) {
    const float maxn = 1.0f - 0.004f;
    float un = fmaxf(norm, 1e-15f);
    float th = ftanh_pos(fminf(un, 15.0f));
    float gs = th * frcp(un);
    float ng = gs * norm;
    float ps = ng > maxn ? maxn * frcp(ng) : 1.0f;
    s = gs * ps;
    float sn = s * norm;
    x2 = sn * sn;
}

// ========== per-edge math, f16 aux (fallback kernels) ==========
__device__ __forceinline__ float2 edge_coef(
    unsigned hu_lo, unsigned hu_hi, unsigned yu_lo, unsigned yu_hi,
    uint4 hsa, uint4 hra, uint4 pqa, const float* wa, float wb) {
    float2 hs01 = upk2(hsa.x), hs23 = upk2(hsa.y), hs4 = upk2(hsa.z), hsxs = upk2(hsa.w);
    float2 hr01 = upk2(hra.x), hr23 = upk2(hra.y), hr4 = upk2(hra.z), hry = upk2(hra.w);
    float2 pq01 = upk2(pqa.x), pq23 = upk2(pqa.y), pq4 = upk2(pqa.z);
    float x2 = hsxs.x, s = hsxs.y, y2 = hry.x;

    float2 hl = upk2(hu_lo), hh = upk2(hu_hi);
    float2 yl = upk2(yu_lo), yh = upk2(yu_hi);

    float p = hl.x * yl.x;
    p = fmaf(hl.y, yl.y, p);
    p = fmaf(hh.x, yh.x, p);
    p = fmaf(hh.y, yh.y, p);
    p += __shfl_xor(p, 1, 64);
    p += __shfl_xor(p, 2, 64);
    p += __shfl_xor(p, 4, 64);
    p += __shfl_xor(p, 8, 64);
    float xy = p * s;

    float z = wb;
    z = fmaf(fmaxf(hs01.x + hr01.x + pq01.x, 0.f), wa[0], z);
    z = fmaf(fmaxf(hs01.y + hr01.y + pq01.y, 0.f), wa[1], z);
    z = fmaf(fmaxf(hs23.x + hr23.x + pq23.x, 0.f), wa[2], z);
    z = fmaf(fmaxf(hs23.y + hr23.y + pq23.y, 0.f), wa[3], z);
    z = fmaf(fmaxf(hs4.x + hr4.x + pq4.x, 0.f), wa[4], z);
    float alpha = frcp(1.f + fexp2_(z * -1.44269504f));

    float Af  = 1.f + 2.f * xy + y2;
    float Bf  = 1.f - x2;
    float den = fmaxf(1.f + 2.f * xy + x2 * y2, 1e-15f);
    float inv = frcp(den);
    float nm2 = fmaxf(fmaf(Af * Af, x2, fmaf(2.f * Af * Bf, xy, Bf * Bf * y2)), 0.f);
    float nm  = fsqrt_(nm2) * inv;
    const float maxn = 1.0f - 0.004f;
    float ps  = nm > maxn ? maxn * frcp(nm) : 1.f;
    float yn  = fmaxf(fminf(nm, maxn), 1e-15f);
    float ratio = (1.f + yn) * frcp(1.f - yn);
    float art = 0.34657359f * flog2_(ratio);
    float k  = inv * ps * alpha * art * frcp(yn);
    return make_float2(k * Af * s, k * Bf);
}

__device__ __forceinline__ void edge_to_global(
    unsigned hu_lo, unsigned hu_hi, unsigned yu_lo, unsigned yu_hi,
    uint4 hsa, uint4 hra, uint4 pqa, const float* wa, float wb,
    bool act, __half2* dst) {
    float2 c = edge_coef(hu_lo, hu_hi, yu_lo, yu_hi, hsa, hra, pqa, wa, wb);
    float2 hl = upk2(hu_lo), hh = upk2(hu_hi);
    float2 yl = upk2(yu_lo), yh = upk2(yu_hi);
    __half2 q_lo = __floats2half2_rn(fmaf(c.x, hl.x, c.y * yl.x), fmaf(c.x, hl.y, c.y * yl.y));
    __half2 q_hi = __floats2half2_rn(fmaf(c.x, hh.x, c.y * yh.x), fmaf(c.x, hh.y, c.y * yh.y));
    if (act) {
        unsafeAtomicAdd(dst, q_lo);
        unsafeAtomicAdd(dst + 16, q_hi);
    }
}

// ========== per-edge math, f32 aux (CSR hot path) ==========
__device__ __forceinline__ float2 edge_coef32(
    unsigned hu_lo, unsigned hu_hi, unsigned yu_lo, unsigned yu_hi,
    float4 hsA, float4 hsB, float4 hrA, float4 hrB, float4 pqA, float pq5,
    const float* wa, float wb) {
    float x2 = hsB.z, s = hsB.w, y2 = hrB.z;
    float2 hl = upk2(hu_lo), hh = upk2(hu_hi);
    float2 yl = upk2(yu_lo), yh = upk2(yu_hi);

    float p = hl.x * yl.x;
    p = fmaf(hl.y, yl.y, p);
    p = fmaf(hh.x, yh.x, p);
    p = fmaf(hh.y, yh.y, p);
    p += __shfl_xor(p, 1, 64);
    p += __shfl_xor(p, 2, 64);
    p += __shfl_xor(p, 4, 64);
    p += __shfl_xor(p, 8, 64);
    float xy = p * s;

    float z = wb;
    z = fmaf(fmaxf(hsA.x + hrA.x + pqA.x, 0.f), wa[0], z);
    z = fmaf(fmaxf(hsA.y + hrA.y + pqA.y, 0.f), wa[1], z);
    z = fmaf(fmaxf(hsA.z + hrA.z + pqA.z, 0.f), wa[2], z);
    z = fmaf(fmaxf(hsA.w + hrA.w + pqA.w, 0.f), wa[3], z);
    z = fmaf(fmaxf(hsB.x + hrB.x + pq5, 0.f), wa[4], z);
    float alpha = frcp(1.f + fexp2_(z * -1.44269504f));

    float Af  = 1.f + 2.f * xy + y2;
    float Bf  = 1.f - x2;
    float den = fmaxf(1.f + 2.f * xy + x2 * y2, 1e-15f);
    float inv = frcp(den);
    float nm2 = fmaxf(fmaf(Af * Af, x2, fmaf(2.f * Af * Bf, xy, Bf * Bf * y2)), 0.f);
    float nm  = fsqrt_(nm2) * inv;
    const float maxn = 1.0f - 0.004f;
    float ps  = nm > maxn ? maxn * frcp(nm) : 1.f;
    float yn  = fmaxf(fminf(nm, maxn), 1e-15f);
    float ratio = (1.f + yn) * frcp(1.f - yn);
    float art = 0.34657359f * flog2_(ratio);
    float k  = inv * ps * alpha * art * frcp(yn);
    return make_float2(k * Af * s, k * Bf);
}

// ================= prep (+cur init for CSR, +packing for fallback) ==========
__global__ void prep_fused16(const int* __restrict__ q_rel,
                             const float* __restrict__ query_embed,
                             const float* __restrict__ Wqr_w,
                             const float* __restrict__ Wqr_b,
                             const float* __restrict__ rela_embed,
                             const float* __restrict__ Wr,
                             const float* __restrict__ hidden,
                             const float* __restrict__ Ws,
                             const int* __restrict__ edges,
                             __half* __restrict__ hidden16,
                             uint4* __restrict__ hs_aux16,
                             __half* __restrict__ hr_h16,
                             uint4* __restrict__ hr_aux16,
                             uint4* __restrict__ preq16,
                             float4* __restrict__ hs_aux32,
                             float4* __restrict__ hr_aux32,
                             float4* __restrict__ preq32,
                             __half* __restrict__ agg16,
                             unsigned long long* __restrict__ packed,
                             int* __restrict__ cur,
                             int N, int R, int B, int E, int NB, int cap,
                             int zero_agg) {
    int wid = (blockIdx.x * blockDim.x + threadIdx.x) >> 6;
    int lane = threadIdx.x & 63;
    int nwaves = (N + 3) >> 2;
    if (wid < nwaves) {
        int q = lane >> 4, j = lane & 15;
        int n = wid * 4 + q;
        bool act = n < N;
        int nc = act ? n : N - 1;

        float4 u = *(const float4*)(hidden + (size_t)nc * 64 + 4 * j);
        float4 w0 = *(const float4*)(Ws + 0 * 64 + 4 * j);
        float4 w1 = *(const float4*)(Ws + 1 * 64 + 4 * j);
        float4 w2 = *(const float4*)(Ws + 2 * 64 + 4 * j);
        float4 w3 = *(const float4*)(Ws + 3 * 64 + 4 * j);
        float4 w4 = *(const float4*)(Ws + 4 * 64 + 4 * j);

#define DOT4(a, b) (fmaf((a).x, (b).x, fmaf((a).y, (b).y, fmaf((a).z, (b).z, (a).w * (b).w))))
        float p0 = DOT4(u, u);
        float p1 = DOT4(u, w0);
        float p2 = DOT4(u, w1);
        float p3 = DOT4(u, w2);
        float p4 = DOT4(u, w3);
        float p5 = DOT4(u, w4);
#undef DOT4
#pragma unroll
        for (int off = 1; off < 16; off <<= 1) {
            p0 += __shfl_xor(p0, off, 64);
            p1 += __shfl_xor(p1, off, 64);
            p2 += __shfl_xor(p2, off, 64);
            p3 += __shfl_xor(p3, off, 64);
            p4 += __shfl_xor(p4, off, 64);
            p5 += __shfl_xor(p5, off, 64);
        }
        float s, x2;
        expmap0_scale(fsqrt_(p0), s, x2);
        if (act) {
            uint2 hp; hp.x = pk2(u.x, u.y); hp.y = pk2(u.z, u.w);
            *(uint2*)(hidden16 + (size_t)n * 64 + 4 * j) = hp;
            if (zero_agg) {
                uint2 zz; zz.x = 0u; zz.y = 0u;
                ((uint2*)(agg16 + (size_t)n * 64))[j] = zz;
            }
            if (j == 0) {
                uint4 o; o.x = pk2(p1, p2); o.y = pk2(p3, p4); o.z = pk2(p5, 0.f); o.w = pk2(x2, s);
                hs_aux16[n] = o;
                if (hs_aux32) {
                    hs_aux32[(size_t)n * 2]     = make_float4(p1, p2, p3, p4);
                    hs_aux32[(size_t)n * 2 + 1] = make_float4(p5, 0.f, x2, s);
                }
            }
        }
        return;
    }
    int w2 = wid - nwaves;
    if (w2 < R) {
        int r = w2;
        float u = rela_embed[r * 64 + lane];
        float p0 = u * u;
        float p1 = u * Wr[0 * 64 + lane];
        float p2 = u * Wr[1 * 64 + lane];
        float p3 = u * Wr[2 * 64 + lane];
        float p4 = u * Wr[3 * 64 + lane];
        float p5 = u * Wr[4 * 64 + lane];
#pragma unroll
        for (int off = 1; off < 64; off <<= 1) {
            p0 += __shfl_xor(p0, off, 64);
            p1 += __shfl_xor(p1, off, 64);
            p2 += __shfl_xor(p2, off, 64);
            p3 += __shfl_xor(p3, off, 64);
            p4 += __shfl_xor(p4, off, 64);
            p5 += __shfl_xor(p5, off, 64);
        }
        float s, y2;
        expmap0_scale(fsqrt_(p0), s, y2);
        hr_h16[r * 64 + lane] = __float2half(s * u);
        if (lane == 0) {
            uint4 o; o.x = pk2(p1, p2); o.y = pk2(p3, p4); o.z = pk2(p5, 0.f); o.w = pk2(y2, 0.f);
            hr_aux16[r] = o;
            if (hr_aux32) {
                hr_aux32[(size_t)r * 2]     = make_float4(p1, p2, p3, p4);
                hr_aux32[(size_t)r * 2 + 1] = make_float4(p5, 0.f, y2, 0.f);
            }
        }
        return;
    }
    int w3 = w2 - R;
    if (w3 < B) {
        int b = w3;
        int qr = q_rel[b];
        float q = query_embed[qr * 64 + lane];
        float p1 = q * Wqr_w[0 * 64 + lane];
        float p2 = q * Wqr_w[1 * 64 + lane];
        float p3 = q * Wqr_w[2 * 64 + lane];
        float p4 = q * Wqr_w[3 * 64 + lane];
        float p5 = q * Wqr_w[4 * 64 + lane];
#pragma unroll
        for (int off = 1; off < 64; off <<= 1) {
            p1 += __shfl_xor(p1, off, 64);
            p2 += __shfl_xor(p2, off, 64);
            p3 += __shfl_xor(p3, off, 64);
            p4 += __shfl_xor(p4, off, 64);
            p5 += __shfl_xor(p5, off, 64);
        }
        if (lane == 0) {
            float b1 = p1 + Wqr_b[0], b2 = p2 + Wqr_b[1], b3 = p3 + Wqr_b[2];
            float b4 = p4 + Wqr_b[3], b5 = p5 + Wqr_b[4];
            uint4 o;
            o.x = pk2(b1, b2); o.y = pk2(b3, b4); o.z = pk2(b5, 0.f); o.w = pk2(0.f, 0.f);
            preq16[b] = o;
            if (preq32) {
                preq32[(size_t)b * 2]     = make_float4(b1, b2, b3, b4);
                preq32[(size_t)b * 2 + 1] = make_float4(b5, 0.f, 0.f, 0.f);
            }
        }
        return;
    }
    int w4 = w3 - B;
    // cur init (CSR path)
    if (cur) {
        int i = w4 * 64 + lane;
        if (i < NB) cur[i] = i * cap;
        else if (i == NB) cur[i] = 0;
        return;
    }
    // edge packing (fallback path)
    int e = w4 * 64 + lane;
    if (e < E) {
        const int* er = edges + (size_t)e * 6;
        int ri  = er[0];
        int rel = er[2];
        int sub = er[4];
        int obj = er[5];
        unsigned long long pk = (unsigned long long)(unsigned)(obj & 0x1ffff)
            | ((unsigned long long)(unsigned)(sub & 0x1ffff) << 17)
            | ((unsigned long long)(unsigned)(rel & 0x1ff) << 34)
            | ((unsigned long long)(unsigned)(ri & 0x1ff) << 43);
        __builtin_nontemporal_store(pk, &packed[e]);
    }
}

// ================= CSR build =================

// pack + bin edges by obj>>7. 4096 edges/block. (validated R8-R13)
__global__ __launch_bounds__(256) void scatter_edges(
    const int* __restrict__ edges, int E, int NB, int cap,
    int* __restrict__ cur,
    unsigned long long* __restrict__ bbuf,
    unsigned long long* __restrict__ ovfbuf, int ovfcap)
{
    __shared__ unsigned long long spk[4096];
    __shared__ int lh[1024];
    __shared__ int lb[1024];
    int t = threadIdx.x;
    int base = blockIdx.x * 4096;
    for (int i = t; i < NB; i += 256) lh[i] = 0;
    __syncthreads();
    int nloc = min(4096, E - base);
    for (int k = t; k < nloc; k += 256) {
        const long long* er = (const long long*)(edges + (size_t)(base + k) * 6);
        long long a = er[0], bq = er[1], cq = er[2];
        int ri = (int)a, rel = (int)bq, sub = (int)cq, obj = (int)(cq >> 32);
        unsigned long long pk = (unsigned long long)(unsigned)(obj & 0x1ffff)
            | ((unsigned long long)(unsigned)(sub & 0x1ffff) << 17)
            | ((unsigned long long)(unsigned)(rel & 0x1ff) << 34)
            | ((unsigned long long)(unsigned)(ri & 0x1ff) << 43);
        spk[k] = pk;
        atomicAdd(&lh[obj >> 7], 1);
    }
    __syncthreads();
    for (int i = t; i < NB; i += 256) {
        int c = lh[i];
        lb[i] = c ? atomicAdd(&cur[i], c) : 0;
    }
    __syncthreads();
    for (int i = t; i < NB; i += 256) lh[i] = 0;
    __syncthreads();
    for (int k = t; k < nloc; k += 256) {
        unsigned long long pk = spk[k];
        int bk = (int)(pk & 0x1ffff) >> 7;
        int rank = atomicAdd(&lh[bk], 1);
        int slot = lb[bk] + rank;
        if (slot < (bk + 1) * cap) {
            bbuf[slot] = pk;
        } else {
            int o = atomicAdd(cur + NB, 1);
            if (o < ovfcap) ovfbuf[o] = pk;
        }
    }
}

// counting-sort each bucket by obj&127; emit per-node [start,end).
__global__ __launch_bounds__(256) void sort_bucket(
    unsigned long long* __restrict__ bbuf,
    const int* __restrict__ cur, int cap,
    int2* __restrict__ nodeoff)
{
    __shared__ unsigned long long spk[4096];
    __shared__ int hist[128];
    __shared__ int pfx[129];
    __shared__ int rk[128];
    int b = blockIdx.x;
    int t = threadIdx.x;
    int start = b * cap;
    int cnt = cur[b] - start;
    if (cnt < 0) cnt = 0;
    if (cnt > cap) cnt = cap;
    if (t < 128) { hist[t] = 0; rk[t] = 0; }
    __syncthreads();
    for (int i = t; i < cnt; i += 256) {
        unsigned long long pk = bbuf[start + i];
        spk[i] = pk;
        atomicAdd(&hist[(int)(pk & 127)], 1);
    }
    __syncthreads();
    if (t == 0) {
        int acc = 0;
#pragma unroll 4
        for (int i = 0; i < 128; ++i) { pfx[i] = acc; acc += hist[i]; }
        pfx[128] = acc;
    }
    __syncthreads();
    if (t < 128) {
        nodeoff[b * 128 + t] = make_int2(start + pfx[t], start + pfx[t + 1]);
    }
    for (int i = t; i < cnt; i += 256) {
        unsigned long long pk = spk[i];
        int loc = (int)(pk & 127);
        int r = atomicAdd(&rk[loc], 1);
        bbuf[start + pfx[loc] + r] = pk;
    }
}

// one WAVE per node: 4 quads process 4 edges/iter, cross-quad reduce, 1 store.
__global__ __launch_bounds__(256) void csr_edge_w(
    const unsigned long long* __restrict__ bbuf,
    const int2* __restrict__ nodeoff,
    const __half* __restrict__ hidden16,
    const __half* __restrict__ hr_h16,
    const float4* __restrict__ hs_aux32,
    const float4* __restrict__ hr_aux32,
    const float4* __restrict__ preq32,
    const float* __restrict__ walpha_w,
    const float* __restrict__ walpha_b,
    __half* __restrict__ agg16,
    int N, int Ntot)
{
    int t = threadIdx.x;
    int lane = t & 63;
    int g = lane >> 4;
    int j = lane & 15;
    int node = blockIdx.x * 4 + (t >> 6);
    if (node >= Ntot) return;

    float wa[5];
    wa[0] = walpha_w[0]; wa[1] = walpha_w[1]; wa[2] = walpha_w[2];
    wa[3] = walpha_w[3]; wa[4] = walpha_w[4];
    float wb = walpha_b[0];

    int2 off = nodeoff[node];
    float a0 = 0.f, a1 = 0.f, a2 = 0.f, a3 = 0.f;
    for (int base = off.x; base < off.y; base += 4) {
        int e = base + g;
        bool act = e < off.y;
        int ec = act ? e : off.y - 1;
        unsigned long long pk = bbuf[ec];
        int sub = (int)((pk >> 17) & 0x1ffff);
        int rel = (int)((pk >> 34) & 0x1ff);
        int ri  = (int)((pk >> 43) & 0x1ff);
        float4 hsA = hs_aux32[(size_t)sub * 2], hsB = hs_aux32[(size_t)sub * 2 + 1];
        float4 hrA = hr_aux32[(size_t)rel * 2], hrB = hr_aux32[(size_t)rel * 2 + 1];
        float4 pqA = preq32[(size_t)ri * 2],   pqB = preq32[(size_t)ri * 2 + 1];
        const unsigned* hrow = (const unsigned*)(hidden16 + (size_t)sub * 64);
        const unsigned* yrow = (const unsigned*)(hr_h16 + (size_t)rel * 64);
        unsigned hu_lo = hrow[j], hu_hi = hrow[16 + j];
        unsigned yu_lo = yrow[j], yu_hi = yrow[16 + j];
        float2 c = edge_coef32(hu_lo, hu_hi, yu_lo, yu_hi,
                               hsA, hsB, hrA, hrB, pqA, pqB.x, wa, wb);
        float gate = act ? 1.f : 0.f;
        float cx = c.x * gate, cy = c.y * gate;
        float2 hl = upk2(hu_lo), hh = upk2(hu_hi);
        float2 yl = upk2(yu_lo), yh = upk2(yu_hi);
        a0 = fmaf(cx, hl.x, fmaf(cy, yl.x, a0));
        a1 = fmaf(cx, hl.y, fmaf(cy, yl.y, a1));
        a2 = fmaf(cx, hh.x, fmaf(cy, yh.x, a2));
        a3 = fmaf(cx, hh.y, fmaf(cy, yh.y, a3));
    }
    // cross-quad reduce (quads hold the same elements for the same node)
    a0 += __shfl_xor(a0, 16, 64); a0 += __shfl_xor(a0, 32, 64);
    a1 += __shfl_xor(a1, 16, 64); a1 += __shfl_xor(a1, 32, 64);
    a2 += __shfl_xor(a2, 16, 64); a2 += __shfl_xor(a2, 32, 64);
    a3 += __shfl_xor(a3, 16, 64); a3 += __shfl_xor(a3, 32, 64);

    if (node < N && g == 0) {
        unsigned* dst = (unsigned*)(agg16 + (size_t)node * 64);
        __builtin_nontemporal_store(pk2(a0, a1), dst + j);
        __builtin_nontemporal_store(pk2(a2, a3), dst + 16 + j);
    }
}

// overflow edges (expected none): global f16 atomics on top of csr rows
__global__ __launch_bounds__(256) void ovf_edge(
    const unsigned long long* __restrict__ ovfbuf,
    const int* __restrict__ ovfcnt_p, int ovfcap,
    const __half* __restrict__ hidden16,
    const __half* __restrict__ hr_h16,
    const uint4* __restrict__ hs_aux16,
    const uint4* __restrict__ hr_aux16,
    const uint4* __restrict__ preq16,
    const float* __restrict__ walpha_w,
    const float* __restrict__ walpha_b,
    __half2* __restrict__ agg)
{
    int cnt = min(*ovfcnt_p, ovfcap);
    if (cnt <= 0) return;
    int j = threadIdx.x & 15;
    int qid = (blockIdx.x * blockDim.x + threadIdx.x) >> 4;
    int nq = (gridDim.x * blockDim.x) >> 4;
    float wa[5];
    wa[0] = walpha_w[0]; wa[1] = walpha_w[1]; wa[2] = walpha_w[2];
    wa[3] = walpha_w[3]; wa[4] = walpha_w[4];
    float wb = walpha_b[0];
    for (int e = qid; e < cnt; e += nq) {
        unsigned long long pk = ovfbuf[e];
        int obj = (int)(pk & 0x1ffff), sub = (int)((pk >> 17) & 0x1ffff);
        int rel = (int)((pk >> 34) & 0x1ff), ri = (int)((pk >> 43) & 0x1ff);
        uint4 hsa = hs_aux16[sub], hra = hr_aux16[rel], pqa = preq16[ri];
        const unsigned* hrow = (const unsigned*)(hidden16 + (size_t)sub * 64);
        const unsigned* yrow = (const unsigned*)(hr_h16 + (size_t)rel * 64);
        edge_to_global(hrow[j], hrow[16 + j], yrow[j], yrow[16 + j],
                       hsa, hra, pqa, wa, wb, true, agg + (size_t)obj * 32 + j);
    }
}

// ================= R11 fallback edge kernel (packed, atomic) =================
__global__ __launch_bounds__(256) void edge_kernel8p(
    const unsigned long long* __restrict__ packed,
    const __half* __restrict__ hidden16,
    const __half* __restrict__ hr_h16,
    const uint4* __restrict__ hs_aux16,
    const uint4* __restrict__ hr_aux16,
    const uint4* __restrict__ preq16,
    const float* __restrict__ walpha_w,
    const float* __restrict__ walpha_b,
    __half2* __restrict__ agg,
    int E)
{
    int wid = (blockIdx.x * blockDim.x + threadIdx.x) >> 6;
    int lane = threadIdx.x & 63;
    int g = lane >> 4;
    int j = lane & 15;

    int e0 = wid * 8 + g;
    int e1 = wid * 8 + 4 + g;
    bool act0 = e0 < E, act1 = e1 < E;

    unsigned long long p0 = __builtin_nontemporal_load(&packed[act0 ? e0 : 0]);
    unsigned long long p1 = __builtin_nontemporal_load(&packed[act1 ? e1 : 0]);
    int obj0 = (int)(p0 & 0x1ffff), sub0 = (int)((p0 >> 17) & 0x1ffff);
    int rel0 = (int)((p0 >> 34) & 0x1ff), r0 = (int)((p0 >> 43) & 0x1ff);
    int obj1 = (int)(p1 & 0x1ffff), sub1 = (int)((p1 >> 17) & 0x1ffff);
    int rel1 = (int)((p1 >> 34) & 0x1ff), r1 = (int)((p1 >> 43) & 0x1ff);

    uint4 hsa0 = hs_aux16[sub0], hra0 = hr_aux16[rel0], pqa0 = preq16[r0];
    uint4 hsa1 = hs_aux16[sub1], hra1 = hr_aux16[rel1], pqa1 = preq16[r1];

    const unsigned* hrow0 = (const unsigned*)(hidden16 + (size_t)sub0 * 64);
    const unsigned* yrow0 = (const unsigned*)(hr_h16 + (size_t)rel0 * 64);
    const unsigned* hrow1 = (const unsigned*)(hidden16 + (size_t)sub1 * 64);
    const unsigned* yrow1 = (const unsigned*)(hr_h16 + (size_t)rel1 * 64);

    float wa[5];
    wa[0] = walpha_w[0]; wa[1] = walpha_w[1]; wa[2] = walpha_w[2];
    wa[3] = walpha_w[3]; wa[4] = walpha_w[4];
    float wb = walpha_b[0];

    edge_to_global(hrow0[j], hrow0[16 + j], yrow0[j], yrow0[16 + j],
                   hsa0, hra0, pqa0, wa, wb, act0, agg + (size_t)obj0 * 32 + j);
    edge_to_global(hrow1[j], hrow1[16 + j], yrow1[j], yrow1[16 + j],
                   hsa1, hra1, pqa1, wa, wb, act1, agg + (size_t)obj1 * 32 + j);
}

// ================= final: one 64-row tile per block =================
__global__ __launch_bounds__(256) void final_gemm16(
    float* __restrict__ out,
    const __half* __restrict__ agg16,
    const float* __restrict__ Wh,
    int N)
{
    __shared__ __half tile[64 * 64];
    int t = threadIdx.x;
    int lane = t & 63;
    int w = t >> 6;

    float wh[64];
    const float4* whr = (const float4*)(Wh + (size_t)lane * 64);
#pragma unroll
    for (int i = 0; i < 16; ++i) {
        float4 v = whr[i];
        wh[4 * i] = v.x; wh[4 * i + 1] = v.y; wh[4 * i + 2] = v.z; wh[4 * i + 3] = v.w;
    }

    int base = blockIdx.x << 6;
    int nrow = min(64, N - base);
    {
        const uint2* src = (const uint2*)(agg16 + (size_t)base * 64);
        uint2* dst = (uint2*)tile;
        int nu2 = nrow * 16;
        for (int i = t; i < nu2; i += 256) dst[i] = src[i];
    }
    __syncthreads();

#pragma unroll 1
    for (int r = 0; r < 16; ++r) {
        int n = base + w * 16 + r;
        if (n >= N) break;
        const uint2* arow = (const uint2*)(tile + (w * 16 + r) * 64);
        float acc = 0.f;
#pragma unroll
        for (int kk = 0; kk < 16; ++kk) {
            uint2 u = arow[kk];
            float2 f0 = upk2(u.x), f1 = upk2(u.y);
            acc = fmaf(f0.x, wh[4 * kk], acc);
            acc = fmaf(f0.y, wh[4 * kk + 1], acc);
            acc = fmaf(f1.x, wh[4 * kk + 2], acc);
            acc = fmaf(f1.y, wh[4 * kk + 3], acc);
        }
        float n2 = wave_sum(acc * acc);
        float na = fsqrt_(n2);
        float nv = fmaxf(na, 1e-10f);
        float pn = ftanh_pos(nv);
        float rinv = frcp(nv);
        float pp = pn * acc * rinv;
        float np = pn * (na * rinv);
        float yn = fmaxf(np, 1e-15f);
        float tt = fminf(yn, 1.f - 1e-5f);
        float ratio = (1.f + tt) * frcp(1.f - tt);
        float art = 0.34657359f * flog2_(ratio);
        __builtin_nontemporal_store(pp * art * frcp(yn), &out[(size_t)n * 64 + lane]);
    }
}

// ================= generic fallback (any A, f32) =================

__global__ void prep_small_kernel(const int* __restrict__ q_rel,
                                  const float* __restrict__ query_embed,
                                  const float* __restrict__ Wqr_w,
                                  const float* __restrict__ Wqr_b,
                                  const float* __restrict__ rela_embed,
                                  const float* __restrict__ Wr,
                                  float* __restrict__ hr_h,
                                  float* __restrict__ hr_aux,
                                  float* __restrict__ preq,
                                  int R, int B, int A) {
    int w = (blockIdx.x * blockDim.x + threadIdx.x) >> 6;
    int lane = threadIdx.x & 63;
    if (w < R) {
        int r = w;
        float u = rela_embed[r * 64 + lane];
        float n2 = wave_sum(u * u);
        float s, y2;
        expmap0_scale(fsqrt_(n2), s, y2);
        hr_h[r * 64 + lane] = s * u;
        for (int a = 0; a < A; ++a) {
            float p = wave_sum(u * Wr[a * 64 + lane]);
            if (lane == 0) hr_aux[r * 8 + a] = p;
        }
        if (lane == 0) hr_aux[r * 8 + 6] = y2;
    } else if (w < R + B) {
        int b = w - R;
        int qr = q_rel[b];
        float q = query_embed[qr * 64 + lane];
        for (int a = 0; a < A; ++a) {
            float p = wave_sum(q * Wqr_w[a * 64 + lane]);
            if (lane == 0) preq[b * 8 + a] = p + Wqr_b[a];
        }
    }
}

__global__ void prep_node_kernel(const float* __restrict__ hidden,
                                 const float* __restrict__ Ws,
                                 float* __restrict__ hs_aux, int N, int A) {
    int w = (blockIdx.x * blockDim.x + threadIdx.x) >> 6;
    if (w >= N) return;
    int lane = threadIdx.x & 63;
    float u = hidden[(size_t)w * 64 + lane];
    float n2 = wave_sum(u * u);
    float s, x2;
    expmap0_scale(fsqrt_(n2), s, x2);
    for (int a = 0; a < A; ++a) {
        float p = wave_sum(u * Ws[a * 64 + lane]);
        if (lane == 0) hs_aux[w * 8 + a] = p;
    }
    if (lane == 0) { hs_aux[w * 8 + 6] = x2; hs_aux[w * 8 + 7] = s; }
}

__global__ void edge_kernel_f32(const int* __restrict__ edges,
                                const float* __restrict__ hidden,
                                const float* __restrict__ hr_h,
                                const float* __restrict__ hr_aux,
                                const float* __restrict__ hs_aux,
                                const float* __restrict__ preq,
                                const float* __restrict__ walpha_w,
                                const float* __restrict__ walpha_b,
                                float* __restrict__ agg,
                                int E, int A) {
    int w = (blockIdx.x * blockDim.x + threadIdx.x) >> 6;
    if (w >= E) return;
    int lane = threadIdx.x & 63;
    const int* er = edges + (size_t)w * 6;
    int r_idx = er[0], rel = er[2], sub = er[4], obj = er[5];

    float s  = hs_aux[(size_t)sub * 8 + 7];
    float x2 = hs_aux[(size_t)sub * 8 + 6];
    float h  = hidden[(size_t)sub * 64 + lane];
    float x  = h * s;
    float y  = hr_h[(size_t)rel * 64 + lane];
    float y2 = hr_aux[(size_t)rel * 8 + 6];
    float xy = wave_sum(x * y);

    float z = walpha_b[0];
    for (int a = 0; a < A; ++a) {
        float pre = hs_aux[(size_t)sub * 8 + a] + hr_aux[(size_t)rel * 8 + a] + preq[(size_t)r_idx * 8 + a];
        z += fmaxf(pre, 0.f) * walpha_w[a];
    }
    float alpha = frcp(1.f + fexp2_(z * -1.44269504f));

    float Af = 1.f + 2.f * xy + y2;
    float Bf = 1.f - x2;
    float den = fmaxf(1.f + 2.f * xy + x2 * y2, 1e-15f);
    float inv = frcp(den);
    float nm2 = fmaxf(Af * Af * x2 + 2.f * Af * Bf * xy + Bf * Bf * y2, 0.f);
    float nm = fsqrt_(nm2) * inv;
    const float maxn = 1.0f - 0.004f;
    float ps = nm > maxn ? maxn * frcp(nm) : 1.f;
    float yn = fmaxf(fminf(nm, maxn), 1e-15f);
    float ratio = (1.f + yn) * frcp(1.f - yn);
    float art = 0.34657359f * flog2_(ratio);
    float k = inv * ps * alpha * art * frcp(yn);
    float msg = fmaf(k * Af * s, h, k * Bf * y);
    unsafeAtomicAdd(agg + (size_t)obj * 64 + lane, msg);
}

__global__ void final_kernel_f32(float* __restrict__ out,
                                 const float* __restrict__ Wh,
                                 int N) {
    __shared__ float WhT[64 * 64];
    int t = threadIdx.x;
    for (int i = t; i < 64 * 64; i += blockDim.x) {
        int row = i >> 6, col = i & 63;
        WhT[col * 64 + row] = Wh[i];
    }
    __syncthreads();

    int lane = t & 63;
    int wl = t >> 6;
    int wpb = blockDim.x >> 6;
    int wg = blockIdx.x * wpb + wl;
    int wstride = gridDim.x * wpb;

    for (int n = wg; n < N; n += wstride) {
        float v = out[(size_t)n * 64 + lane];
        float a = 0.f;
#pragma unroll
        for (int k = 0; k < 64; ++k)
            a = fmaf(__shfl(v, k, 64), WhT[k * 64 + lane], a);

        float n2 = wave_sum(a * a);
        float na = fsqrt_(n2);
        float nv = fmaxf(na, 1e-10f);
        float pn = tanhf(nv);
        float rinv = frcp(nv);
        float pp = pn * a * rinv;
        float np = pn * (na * rinv);
        float yn = fmaxf(np, 1e-15f);
        float tt = fminf(yn, 1.f - 1e-5f);
        float ratio = (1.f + tt) * frcp(1.f - tt);
        float art = 0.34657359f * flog2_(ratio);
        out[(size_t)n * 64 + lane] = pp * art * frcp(yn);
    }
}

extern "C" void kernel_launch(void* const* d_in, const int* in_sizes, int n_in,
                              void* d_out, int out_size, void* d_ws, size_t ws_size,
                              hipStream_t stream) {
    const int*   q_rel       = (const int*)d_in[1];
    const float* hidden      = (const float*)d_in[2];
    const int*   edges       = (const int*)d_in[3];
    const float* rela_embed  = (const float*)d_in[6];
    const float* query_embed = (const float*)d_in[7];
    const float* Ws          = (const float*)d_in[8];
    const float* Wr          = (const float*)d_in[9];
    const float* Wqr_w       = (const float*)d_in[10];
    const float* Wqr_b       = (const float*)d_in[11];
    const float* walpha_w    = (const float*)d_in[12];
    const float* walpha_b    = (const float*)d_in[13];
    const float* Wh          = (const float*)d_in[14];

    const int D = 64;
    int B = in_sizes[0];
    int E = in_sizes[3] / 6;
    int A = in_sizes[11];
    int R = in_sizes[6] / D;
    int N = out_size / D;

    float* out = (float*)d_out;

    size_t agg_b     = (size_t)N * 128;
    size_t hid16_b   = (size_t)N * 128;
    size_t hsaux_b   = (size_t)N * 16;
    size_t hrh_b     = (size_t)R * 128;
    size_t hraux_b   = (size_t)R * 16;
    size_t preq_b    = (size_t)B * 16;
    size_t hsaux32_b = (size_t)N * 32;
    size_t hraux32_b = (size_t)R * 32;
    size_t preq32_b  = (size_t)B * 32;
    size_t need16    = agg_b + hid16_b + hsaux_b + hrh_b + hraux_b + preq_b;
    size_t packed_b  = (size_t)E * 8;
    size_t need_pk   = need16 + packed_b;

    int NB = (N + 127) >> 7;
    int Ntot = NB * 128;
    int cap = (NB > 0) ? 2 * ((E + NB - 1) / NB) : 512;
    if (cap < 512) cap = 512;
    int ovfcap = 65536;
    size_t bbuf_b = (size_t)NB * (size_t)cap * 8;
    size_t cur_b  = (((size_t)NB + 1) * 4 + 15) & ~(size_t)15;
    size_t noff_b = (size_t)Ntot * 8;
    size_t ovf_b  = (size_t)ovfcap * 8;
    size_t need_csr = need16 + hsaux32_b + hraux32_b + preq32_b +
                      bbuf_b + cur_b + noff_b + ovf_b;

    bool fields_ok = (N > 0) && (N <= 131072) && (R <= 512) && (B <= 512);
    bool csr_ok = (A == 5) && fields_ok && (NB <= 1024) && (E > 0) &&
                  (cap <= 4096) && ((long long)NB * cap < (1LL << 31)) &&
                  (ws_size >= need_csr);
    bool pkpath = (A == 5) && fields_ok && (ws_size >= need_pk);

    if (csr_ok) {
        char* base = (char*)d_ws;
        __half* agg16    = (__half*)base;            base += agg_b;
        __half* hidden16 = (__half*)base;            base += hid16_b;
        uint4*  hs_aux16 = (uint4*)base;             base += hsaux_b;
        __half* hr_h16   = (__half*)base;            base += hrh_b;
        uint4*  hr_aux16 = (uint4*)base;             base += hraux_b;
        uint4*  preq16   = (uint4*)base;             base += preq_b;
        float4* hs_aux32 = (float4*)base;            base += hsaux32_b;
        float4* hr_aux32 = (float4*)base;            base += hraux32_b;
        float4* preq32   = (float4*)base;            base += preq32_b;
        unsigned long long* bbuf = (unsigned long long*)base; base += bbuf_b;
        int* cur = (int*)base;                       base += cur_b;
        int2* nodeoff = (int2*)base;                 base += noff_b;
        unsigned long long* ovfbuf = (unsigned long long*)base;

        int nwaves = (N + 3) / 4;
        int curwaves = (NB + 1 + 63) / 64;
        int total_waves = nwaves + R + B + curwaves;
        prep_fused16<<<(total_waves + 3) / 4, 256, 0, stream>>>(
            q_rel, query_embed, Wqr_w, Wqr_b, rela_embed, Wr,
            hidden, Ws, edges, hidden16, hs_aux16, hr_h16, hr_aux16, preq16,
            hs_aux32, hr_aux32, preq32, agg16,
            (unsigned long long*)nullptr, cur, N, R, B, 0, NB, cap, 0);

        scatter_edges<<<(E + 4095) / 4096, 256, 0, stream>>>(
            edges, E, NB, cap, cur, bbuf, ovfbuf, ovfcap);

        sort_bucket<<<NB, 256, 0, stream>>>(bbuf, cur, cap, nodeoff);

        csr_edge_w<<<(Ntot + 3) / 4, 256, 0, stream>>>(
            bbuf, nodeoff, hidden16, hr_h16, hs_aux32, hr_aux32, preq32,
            walpha_w, walpha_b, agg16, N, Ntot);

        ovf_edge<<<64, 256, 0, stream>>>(
            ovfbuf, cur + NB, ovfcap, hidden16, hr_h16, hs_aux16, hr_aux16,
            preq16, walpha_w, walpha_b, (__half2*)agg16);

        int ntiles = (N + 63) / 64;
        final_gemm16<<<ntiles, 256, 0, stream>>>(out, agg16, Wh, N);
    } else if (pkpath) {
        char* base = (char*)d_ws;
        __half2* agg      = (__half2*)base;          base += agg_b;
        __half*  hidden16 = (__half*)base;           base += hid16_b;
        uint4*   hs_aux16 = (uint4*)base;            base += hsaux_b;
        __half*  hr_h16   = (__half*)base;           base += hrh_b;
        uint4*   hr_aux16 = (uint4*)base;            base += hraux_b;
        uint4*   preq16   = (uint4*)base;            base += preq_b;
        unsigned long long* packed = (unsigned long long*)base;

        int nwaves = (N + 3) / 4;
        int ewavesP = (E + 63) / 64;
        int total_waves = nwaves + R + B + ewavesP;
        prep_fused16<<<(total_waves + 3) / 4, 256, 0, stream>>>(
            q_rel, query_embed, Wqr_w, Wqr_b, rela_embed, Wr,
            hidden, Ws, edges, hidden16, hs_aux16, hr_h16, hr_aux16, preq16,
            (float4*)nullptr, (float4*)nullptr, (float4*)nullptr, (__half*)agg,
            packed, (int*)nullptr, N, R, B, E, 0, 0, 1);

        int ewaves = (E + 7) / 8;
        edge_kernel8p<<<(ewaves + 3) / 4, 256, 0, stream>>>(
            packed, hidden16, hr_h16, hs_aux16, hr_aux16, preq16,
            walpha_w, walpha_b, agg, E);

        int ntiles = (N + 63) / 64;
        final_gemm16<<<ntiles, 256, 0, stream>>>(out, (const __half*)agg, Wh, N);
    } else {
        float* hs_aux = (float*)d_ws;
        float* hr_h   = hs_aux + (size_t)N * 8;
        float* hr_aux = hr_h + (size_t)R * 64;
        float* preq   = hr_aux + (size_t)R * 8;

        (void)hipMemsetAsync(d_out, 0, (size_t)out_size * sizeof(float), stream);

        int waves_small = R + B;
        prep_small_kernel<<<(waves_small * 64 + 255) / 256, 256, 0, stream>>>(
            q_rel, query_embed, Wqr_w, Wqr_b, rela_embed, Wr,
            hr_h, hr_aux, preq, R, B, A);

        prep_node_kernel<<<(N + 3) / 4, 256, 0, stream>>>(hidden, Ws, hs_aux, N, A);

        edge_kernel_f32<<<(E + 3) / 4, 256, 0, stream>>>(
            edges, hidden, hr_h, hr_aux, hs_aux, preq,
            walpha_w, walpha_b, out, E, A);

        final_kernel_f32<<<1024, 256, 0, stream>>>(out, Wh, N);
    }
}